// Round 13
// baseline (227.500 us; speedup 1.0000x reference)
//
#include <hip/hip_runtime.h>
#include <hip/hip_bf16.h>
#include <math.h>

typedef __attribute__((ext_vector_type(8))) short short8;
typedef __attribute__((ext_vector_type(4))) float f32x4;

#define NN 10000
#define EE 320000
#define NHEAD 16
#define EPSf 1e-5f

// ---------- bf16 helpers ----------
__device__ __forceinline__ unsigned short f2bf(float f) {
    union { float f; unsigned u; } v; v.f = f;
    unsigned u = v.u;
    u += 0x7fffu + ((u >> 16) & 1u);   // RNE
    return (unsigned short)(u >> 16);
}
__device__ __forceinline__ unsigned pk2(float a, float b) {
    __hip_bfloat162 t = __float22bfloat162_rn(make_float2(a, b));
    return *reinterpret_cast<unsigned*>(&t);
}

// sEX/sVl overlays on Y's k-half byte region (rows 0..15 / 16..31)
__device__ __forceinline__ float& sEXat(unsigned short* sR, int ix) {
    return *(float*)(sR + ((ix >> 6) << 8) + ((ix & 63) << 1));
}
__device__ __forceinline__ float& sVLat(unsigned short* sR, int ix) {
    return *(float*)(sR + 4096 + ((ix >> 6) << 8) + ((ix & 63) << 1));
}

// ed-tile slot: 12 chunks/row, XOR swizzle within aligned groups (8 + 4)
__device__ __forceinline__ int edslot(int r, int cl) {
    int c = (cl < 8) ? (cl ^ (r & 7)) : (8 + ((cl & 3) ^ (r & 3)));
    return r * 96 + (c << 3);
}

// ---------- fused: hist (1250) + prep (1802) ----------
// Wt1 ed-block k' order: [gauss(80) | ea(4) | zeros(12)]
#define PRE_HIST 1250
#define PRE_PREP 1802
__global__ __launch_bounds__(256) void k_pre(
    const int* __restrict__ ei, int* __restrict__ cnt,
    const float* __restrict__ h,
    const float* __restrict__ kW1, const float* __restrict__ vW1,
    const float* __restrict__ kW2, const float* __restrict__ vW2,
    const float* __restrict__ qW1, const float* __restrict__ qW2,
    unsigned short* __restrict__ h_bf, unsigned short* __restrict__ Wt1,
    unsigned short* __restrict__ kW2t, unsigned short* __restrict__ vW2t,
    unsigned short* __restrict__ qW1t, unsigned short* __restrict__ qW2t)
{
    const int tid = threadIdx.x;
    int b = blockIdx.x;

    if (b < PRE_HIST) {                       // ---- histogram ----
        int e = b * 256 + tid;                // EE = 1250*256 exactly
        atomicAdd(&cnt[ei[EE + e]], 1);
        return;
    }
    b -= PRE_HIST;                            // ---- prep ----
    int i = b * 256 + tid;
    if (i < 320000) {                         // h: 4 elements per thread
        float4 v = *(const float4*)(h + i * 4);
        uint2 o; o.x = pk2(v.x, v.y); o.y = pk2(v.z, v.w);
        *(uint2*)(h_bf + i * 4) = o;
        return;
    }
    int j = i - 320000;
    if (j < 256 * 352) {
        int n = j / 352, k = j % 352;
        float val = 0.f;
        int pk = -1;
        if (k < 128)      pk = 84 + k;            // h_dst
        else if (k < 256) pk = 212 + (k - 128);   // h_src
        else if (k < 336) pk = 4 + (k - 256);     // gauss
        else if (k < 340) pk = k - 336;           // ea
        if (pk >= 0)
            val = (n < 128) ? kW1[pk * 128 + n] : vW1[pk * 128 + (n - 128)];
        Wt1[j] = f2bf(val); return;
    }
    j -= 256 * 352;
    if (j < 128 * 128) { int n = j >> 7, k = j & 127; kW2t[j] = f2bf(kW2[k * 128 + n]); return; }
    j -= 128 * 128;
    if (j < 16 * 128)  { int n = j >> 7, k = j & 127; vW2t[j] = f2bf(vW2[k * 16 + n]); return; }
    j -= 16 * 128;
    if (j < 128 * 128) { int n = j >> 7, k = j & 127; qW1t[j] = f2bf(qW1[k * 128 + n]); return; }
    j -= 128 * 128;
    if (j < 128 * 128) { int n = j >> 7, k = j & 127; qW2t[j] = f2bf(qW2[k * 128 + n]); return; }
}

// ---------------------- scan (wave-based) ----------------------
__global__ __launch_bounds__(1024) void k_scan(const int* __restrict__ cnt,
                                               int* __restrict__ cnt2) {
    __shared__ int wsum[16];
    const int t = threadIdx.x;
    const int lane = t & 63, w = t >> 6;
    int loc[10];
    int s = 0;
    #pragma unroll
    for (int i = 0; i < 10; ++i) {
        int idx = t * 10 + i;
        loc[i] = (idx < NN) ? cnt[idx] : 0;
        s += loc[i];
    }
    int sc = s;
    #pragma unroll
    for (int off = 1; off < 64; off <<= 1) {
        int v = __shfl_up(sc, off, 64);
        if (lane >= off) sc += v;
    }
    if (lane == 63) wsum[w] = sc;
    __syncthreads();
    if (w == 0) {
        int v = (lane < 16) ? wsum[lane] : 0;
        int c = v;
        #pragma unroll
        for (int off = 1; off < 16; off <<= 1) {
            int t2 = __shfl_up(c, off, 64);
            if (lane >= off) c += t2;
        }
        if (lane < 16) wsum[lane] = c - v;
    }
    __syncthreads();
    int run = wsum[w] + sc - s;
    #pragma unroll
    for (int i = 0; i < 10; ++i) {
        int idx = t * 10 + i;
        if (idx < NN) { cnt2[idx] = run; run += loc[i]; }
    }
}

// ---- fused: place+edata+features (1250) + q-MLP (157) + c-table (157) ----
#define PQ_PLACE 1250
#define PQ_QMLP  157
#define PQ_CPREP 157
__global__ __launch_bounds__(256) void k_placeq(
    const int* __restrict__ ei, int* __restrict__ cnt2,
    const float* __restrict__ x, const float* __restrict__ ea,
    float* __restrict__ edata2, unsigned short* __restrict__ featbf,
    const unsigned short* __restrict__ h_bf,
    const unsigned short* __restrict__ Wt1,
    const float* __restrict__ kb1, const float* __restrict__ vb1,
    const unsigned short* __restrict__ qW1t, const float* __restrict__ qb1,
    const float* __restrict__ qg,  const float* __restrict__ qbt,
    const unsigned short* __restrict__ qW2t, const float* __restrict__ qb2,
    float* __restrict__ qout,
    float* __restrict__ cdst, unsigned short* __restrict__ csrc_bf)
{
    __shared__ __align__(16) unsigned short sQ[64 * 128];
    __shared__ float2 sSt[4 * 64];
    const int tid = threadIdx.x;
    int b = blockIdx.x;

    if (b < PQ_PLACE) {                       // ---- place + edata2 + featbf ----
        int e = b * 256 + tid;
        int s = ei[e], d = ei[EE + e];
        int slot = atomicAdd(&cnt2[d], 1);
        float rx = x[d*3+0] - x[s*3+0];
        float ry = x[d*3+1] - x[s*3+1];
        float rz = x[d*3+2] - x[s*3+2];
        float dist = sqrtf(rx*rx + ry*ry + rz*rz);
        float4 eav = *(const float4*)(ea + e * 4);
        float* ep = edata2 + (size_t)slot * 8;
        ep[0] = rx; ep[1] = ry; ep[2] = rz; ep[3] = 0.f;
        unsigned* epu = (unsigned*)ep;
        epu[4] = pk2(eav.x, eav.y);
        epu[5] = pk2(eav.z, eav.w);
        ((int*)ep)[6] = s; ((int*)ep)[7] = d;
        // gaussian features, k' order j=0..79: f=j/20, g=j%20
        const float step  = 10.0f / 19.0f;
        const float coeff = -0.5f / (step * step);
        unsigned* fp = (unsigned*)(featbf + (size_t)slot * 80);
        float eaf[4] = {eav.x, eav.y, eav.z, eav.w};
        #pragma unroll
        for (int f = 0; f < 4; ++f) {
            #pragma unroll
            for (int g2 = 0; g2 < 10; ++g2) {
                float d0 = dist - (float)(g2 * 2)     * step;
                float d1 = dist - (float)(g2 * 2 + 1) * step;
                fp[f * 10 + g2] = pk2(eaf[f] * __expf(coeff * d0 * d0),
                                      eaf[f] * __expf(coeff * d1 * d1));
            }
        }
        return;
    }
    b -= PQ_PLACE;
    const int lane = tid & 63, wv = tid >> 6, rA = lane & 15, kq = lane >> 4;
    f32x4 zf = {0.f, 0.f, 0.f, 0.f};

    if (b >= PQ_QMLP) {                       // ---- c-table precompute ----
        b -= PQ_QMLP;
        const int n0c = b * 64;
        #pragma unroll
        for (int it = 0; it < 4; ++it) {
            int p = tid + it * 256;
            int r = p >> 4, c = p & 15;
            int node = n0c + r; if (node >= NN) node = NN - 1;
            uint4 v = *(const uint4*)(h_bf + node * 128 + c * 8);
            *(uint4*)(sQ + r * 128 + ((c ^ (r & 7)) << 3)) = v;
        }
        __syncthreads();
        const int n0w = wv * 64;              // 4 waves x 64 cols
        #pragma unroll
        for (int T = 0; T < 2; ++T) {
            const int Toff = T << 7;
            f32x4 a[4][4];
            #pragma unroll
            for (int nf = 0; nf < 4; ++nf)
                #pragma unroll
                for (int ef = 0; ef < 4; ++ef) a[nf][ef] = zf;
            for (int k0 = 0; k0 < 128; k0 += 32) {
                int cb = (k0 >> 3) + kq;
                short8 wf[4], kv[4];
                #pragma unroll
                for (int nf = 0; nf < 4; ++nf)
                    wf[nf] = *(const short8*)(Wt1 + (n0w + nf * 16 + rA) * 352 + Toff + k0 + kq * 8);
                #pragma unroll
                for (int ef = 0; ef < 4; ++ef) {
                    int r = ef * 16 + rA;
                    kv[ef] = *(const short8*)(sQ + r * 128 + ((cb ^ (r & 7)) << 3));
                }
                #pragma unroll
                for (int nf = 0; nf < 4; ++nf)
                    #pragma unroll
                    for (int ef = 0; ef < 4; ++ef)
                        a[nf][ef] = __builtin_amdgcn_mfma_f32_16x16x32_bf16(wf[nf], kv[ef], a[nf][ef], 0, 0, 0);
            }
            if (T == 0) {
                #pragma unroll
                for (int nf = 0; nf < 4; ++nf) {
                    int col = n0w + nf * 16 + kq * 4;
                    f32x4 bb = (col < 128) ? *(const f32x4*)(kb1 + col)
                                           : *(const f32x4*)(vb1 + col - 128);
                    #pragma unroll
                    for (int ef = 0; ef < 4; ++ef) {
                        int node = n0c + ef * 16 + rA;
                        if (node < NN) {
                            f32x4 o;
                            #pragma unroll
                            for (int j = 0; j < 4; ++j) o[j] = a[nf][ef][j] + bb[j];
                            *(f32x4*)(cdst + (size_t)node * 256 + col) = o;
                        }
                    }
                }
            } else {
                #pragma unroll
                for (int nf = 0; nf < 4; ++nf) {
                    int col = n0w + nf * 16 + kq * 4;
                    #pragma unroll
                    for (int ef = 0; ef < 4; ++ef) {
                        int node = n0c + ef * 16 + rA;
                        if (node < NN) {
                            uint2 pw;
                            pw.x = pk2(a[nf][ef][0], a[nf][ef][1]);
                            pw.y = pk2(a[nf][ef][2], a[nf][ef][3]);
                            *(uint2*)(csrc_bf + (size_t)node * 256 + col) = pw;
                        }
                    }
                }
            }
        }
        return;
    }
    // ---- q-MLP (MFMA) ----
    const int n0q = b * 64;
    #pragma unroll
    for (int it = 0; it < 4; ++it) {
        int p = tid + it * 256;
        int r = p >> 4, c = p & 15;
        int node = n0q + r; if (node >= NN) node = NN - 1;
        uint4 v = *(const uint4*)(h_bf + node * 128 + c * 8);
        *(uint4*)(sQ + r * 128 + ((c ^ (r & 7)) << 3)) = v;
    }
    __syncthreads();

    const int nb = wv * 32;
    f32x4 acc[2][4];
    #pragma unroll
    for (int nf = 0; nf < 2; ++nf)
        #pragma unroll
        for (int ef = 0; ef < 4; ++ef) acc[nf][ef] = zf;

    for (int k0 = 0; k0 < 128; k0 += 32) {
        int cb = (k0 >> 3) + kq;
        short8 wf[2], kv[4];
        #pragma unroll
        for (int nf = 0; nf < 2; ++nf)
            wf[nf] = *(const short8*)(qW1t + (nb + nf * 16 + rA) * 128 + k0 + kq * 8);
        #pragma unroll
        for (int ef = 0; ef < 4; ++ef) {
            int r = ef * 16 + rA;
            kv[ef] = *(const short8*)(sQ + r * 128 + ((cb ^ (r & 7)) << 3));
        }
        #pragma unroll
        for (int nf = 0; nf < 2; ++nf)
            #pragma unroll
            for (int ef = 0; ef < 4; ++ef)
                acc[nf][ef] = __builtin_amdgcn_mfma_f32_16x16x32_bf16(wf[nf], kv[ef], acc[nf][ef], 0, 0, 0);
    }
    #pragma unroll
    for (int nf = 0; nf < 2; ++nf) {
        f32x4 bb = *(const f32x4*)(qb1 + nb + nf * 16 + kq * 4);
        #pragma unroll
        for (int ef = 0; ef < 4; ++ef)
            #pragma unroll
            for (int j = 0; j < 4; ++j) acc[nf][ef][j] += bb[j];
    }
    float sm[4], sq2[4];
    #pragma unroll
    for (int ef = 0; ef < 4; ++ef) {
        float s = 0.f, s2 = 0.f;
        #pragma unroll
        for (int nf = 0; nf < 2; ++nf)
            #pragma unroll
            for (int j = 0; j < 4; ++j) { float v = acc[nf][ef][j]; s += v; s2 += v * v; }
        s  += __shfl_xor(s, 16, 64);  s  += __shfl_xor(s, 32, 64);
        s2 += __shfl_xor(s2, 16, 64); s2 += __shfl_xor(s2, 32, 64);
        sm[ef] = s; sq2[ef] = s2;
    }
    if (kq == 0) {
        #pragma unroll
        for (int ef = 0; ef < 4; ++ef)
            sSt[wv * 64 + ef * 16 + rA] = make_float2(sm[ef], sq2[ef]);
    }
    __syncthreads();

    {
        f32x4 g4[2], b4[2];
        #pragma unroll
        for (int nf = 0; nf < 2; ++nf) {
            g4[nf] = *(const f32x4*)(qg  + nb + nf * 16 + kq * 4);
            b4[nf] = *(const f32x4*)(qbt + nb + nf * 16 + kq * 4);
        }
        #pragma unroll
        for (int ef = 0; ef < 4; ++ef) {
            int r = ef * 16 + rA;
            float ts = 0.f, ts2 = 0.f;
            #pragma unroll
            for (int w2 = 0; w2 < 4; ++w2) {
                float2 p = sSt[w2 * 64 + r];
                ts += p.x; ts2 += p.y;
            }
            float mu  = ts * (1.f / 128.f);
            float var = ts2 * (1.f / 128.f) - mu * mu;
            float rs  = rsqrtf(var + EPSf);
            #pragma unroll
            for (int nf = 0; nf < 2; ++nf) {
                float y[4];
                #pragma unroll
                for (int j = 0; j < 4; ++j) {
                    float f = (acc[nf][ef][j] - mu) * rs * g4[nf][j] + b4[nf][j];
                    y[j] = f > 0.f ? f : 0.f;
                }
                int col = nb + nf * 16 + kq * 4;
                int ch = col >> 3;
                uint2 pw; pw.x = pk2(y[0], y[1]); pw.y = pk2(y[2], y[3]);
                *(uint2*)(sQ + r * 128 + ((ch ^ (r & 7)) << 3) + (col & 7)) = pw;
            }
        }
    }
    __syncthreads();

    f32x4 a2[2][4];
    #pragma unroll
    for (int nf = 0; nf < 2; ++nf)
        #pragma unroll
        for (int ef = 0; ef < 4; ++ef) a2[nf][ef] = zf;
    for (int k0 = 0; k0 < 128; k0 += 32) {
        int cb = (k0 >> 3) + kq;
        short8 wf[2], yv[4];
        #pragma unroll
        for (int nf = 0; nf < 2; ++nf)
            wf[nf] = *(const short8*)(qW2t + (nb + nf * 16 + rA) * 128 + k0 + kq * 8);
        #pragma unroll
        for (int ef = 0; ef < 4; ++ef) {
            int r = ef * 16 + rA;
            yv[ef] = *(const short8*)(sQ + r * 128 + ((cb ^ (r & 7)) << 3));
        }
        #pragma unroll
        for (int nf = 0; nf < 2; ++nf)
            #pragma unroll
            for (int ef = 0; ef < 4; ++ef)
                a2[nf][ef] = __builtin_amdgcn_mfma_f32_16x16x32_bf16(wf[nf], yv[ef], a2[nf][ef], 0, 0, 0);
    }
    #pragma unroll
    for (int nf = 0; nf < 2; ++nf) {
        f32x4 bb = *(const f32x4*)(qb2 + nb + nf * 16 + kq * 4);
        #pragma unroll
        for (int ef = 0; ef < 4; ++ef) {
            int node = n0q + ef * 16 + rA;
            if (node < NN) {
                f32x4 o;
                #pragma unroll
                for (int j = 0; j < 4; ++j) o[j] = a2[nf][ef][j] + bb[j];
                *(f32x4*)(qout + node * 128 + nb + nf * 16 + kq * 4) = o;
            }
        }
    }
}

// ------- per-slot kernel: pre-barrier gathers+staging, c-seeded acc, K=96 ed-MFMA -------
__global__ __launch_bounds__(512) void k_edge(
    const float* __restrict__ edata2, const unsigned short* __restrict__ featbf,
    const unsigned short* __restrict__ Wt1,
    const float* __restrict__ cdst, const unsigned short* __restrict__ csrc_bf,
    const float* __restrict__ kg, const float* __restrict__ kbt,
    const float* __restrict__ vg, const float* __restrict__ vbt,
    const unsigned short* __restrict__ kW2t, const float* __restrict__ kb2,
    const unsigned short* __restrict__ vW2t, const float* __restrict__ vb2,
    const float* __restrict__ q,
    float* __restrict__ Dg, float* __restrict__ Pg)
{
    // sY (32KB) time-multiplexed: ed tile [64][96] -> Y [64][256] -> EX/V overlay.
    __shared__ __align__(16) unsigned short sY[64 * 256];
    __shared__ float2 sStats[8 * 64];
    __shared__ float sRel[64 * 3];
    __shared__ int   sSrc[64], sDst[64];
    unsigned short* sED = sY;   // alias (layout per edslot)

    const int tid  = threadIdx.x;
    const int e0   = blockIdx.x * 64;
    const int lane = tid & 63;
    const int wv   = tid >> 6;          // 0..7
    const int rA   = lane & 15;
    const int kq   = lane >> 4;

    // ---- prologue (scan data only; nothing below waits on it until the scan) ----
    if (tid < 64) {
        const float* ep = edata2 + (size_t)(e0 + tid) * 8;
        f32x4 w0 = *(const f32x4*)ep;
        int2  sd = *(const int2*)((const int*)ep + 6);
        sRel[tid*3+0] = w0[0]; sRel[tid*3+1] = w0[1]; sRel[tid*3+2] = w0[2];
        sSrc[tid] = sd.x; sDst[tid] = sd.y;
    }

    // ---- per-thread src/dst for c-gather (direct global, L1-hot) ----
    const int n0 = wv * 32;
    int dn[4], sn[4];
    #pragma unroll
    for (int ef = 0; ef < 4; ++ef) {
        int2 sd = *(const int2*)((const int*)edata2 + (size_t)(e0 + ef * 16 + rA) * 8 + 6);
        sn[ef] = sd.x; dn[ef] = sd.y;
    }
    // issue c-gather loads (consumed after barrier)
    f32x4 cdv[2][4];
    uint2 csv[2][4];
    #pragma unroll
    for (int ef = 0; ef < 4; ++ef)
        #pragma unroll
        for (int nf = 0; nf < 2; ++nf) {
            cdv[nf][ef] = *(const f32x4*)(cdst + (size_t)dn[ef] * 256 + n0 + nf * 16 + kq * 4);
            csv[nf][ef] = *(const uint2*)(csrc_bf + (size_t)sn[ef] * 256 + n0 + nf * 16 + kq * 4);
        }

    // ---- stage ed features: coalesced featbf burst + ea/zero tail ----
    #pragma unroll
    for (int it = 0; it < 2; ++it) {
        int p = tid + it * 512;
        if (p < 640) {
            int r = (p * 6554) >> 16;        // p / 10
            int cl = p - r * 10;
            uint4 v = *(const uint4*)(featbf + (size_t)(e0 + r) * 80 + cl * 8);
            *(uint4*)(sED + edslot(r, cl)) = v;
        }
    }
    if (tid < 128) {
        int r = tid >> 1, which = tid & 1;
        uint4 v = {0u, 0u, 0u, 0u};
        if (which == 0) {
            const unsigned* eu = (const unsigned*)edata2 + (size_t)(e0 + r) * 8;
            v.x = eu[4]; v.y = eu[5];
        }
        *(uint4*)(sED + edslot(r, 10 + which)) = v;
    }
    __syncthreads();

    // ---- seed acc (gather loads have drained under staging) ----
    f32x4 zf = {0.f, 0.f, 0.f, 0.f};
    f32x4 acc[2][4];
    #pragma unroll
    for (int ef = 0; ef < 4; ++ef)
        #pragma unroll
        for (int nf = 0; nf < 2; ++nf) {
            f32x4 cs;
            cs[0] = __uint_as_float(csv[nf][ef].x << 16);
            cs[1] = __uint_as_float(csv[nf][ef].x & 0xFFFF0000u);
            cs[2] = __uint_as_float(csv[nf][ef].y << 16);
            cs[3] = __uint_as_float(csv[nf][ef].y & 0xFFFF0000u);
            acc[nf][ef] = cdv[nf][ef] + cs;
        }

    // ---- ed MFMA: K = 96 (weights at Wt1 k' 256..351) ----
    #pragma unroll
    for (int s = 0; s < 3; ++s) {
        int k0 = s * 32;
        short8 wfr[2], kv[4];
        #pragma unroll
        for (int nf = 0; nf < 2; ++nf)
            wfr[nf] = *(const short8*)(Wt1 + (n0 + nf * 16 + rA) * 352 + 256 + k0 + kq * 8);
        #pragma unroll
        for (int ef = 0; ef < 4; ++ef) {
            int r = ef * 16 + rA;
            kv[ef] = *(const short8*)(sED + edslot(r, s * 4 + kq));
        }
        #pragma unroll
        for (int nf = 0; nf < 2; ++nf)
            #pragma unroll
            for (int ef = 0; ef < 4; ++ef)
                acc[nf][ef] = __builtin_amdgcn_mfma_f32_16x16x32_bf16(wfr[nf], kv[ef], acc[nf][ef], 0, 0, 0);
    }

    // ---- in-register LN stats ----
    float sm[4], sq2[4];
    #pragma unroll
    for (int ef = 0; ef < 4; ++ef) {
        float s = 0.f, s2 = 0.f;
        #pragma unroll
        for (int nf = 0; nf < 2; ++nf)
            #pragma unroll
            for (int j = 0; j < 4; ++j) { float v = acc[nf][ef][j]; s += v; s2 += v * v; }
        s  += __shfl_xor(s, 16, 64);  s  += __shfl_xor(s, 32, 64);
        s2 += __shfl_xor(s2, 16, 64); s2 += __shfl_xor(s2, 32, 64);
        sm[ef] = s; sq2[ef] = s2;
    }
    if (kq == 0) {
        #pragma unroll
        for (int ef = 0; ef < 4; ++ef)
            sStats[wv * 64 + ef * 16 + rA] = make_float2(sm[ef], sq2[ef]);
    }
    __syncthreads();   // stats ready; separates sED reads from sY writes

    // ---- normalize + ReLU + pack -> Y ----
    {
        const float* gp = (wv < 4) ? kg : vg;
        const float* bp = (wv < 4) ? kbt : vbt;
        const int sb = (wv < 4) ? 0 : 4;
        f32x4 g4[2], b4[2];
        #pragma unroll
        for (int nf = 0; nf < 2; ++nf) {
            int cl = (wv & 3) * 32 + nf * 16 + kq * 4;
            g4[nf] = *(const f32x4*)(gp + cl);
            b4[nf] = *(const f32x4*)(bp + cl);
        }
        #pragma unroll
        for (int ef = 0; ef < 4; ++ef) {
            int e = ef * 16 + rA;
            float ts = 0.f, ts2 = 0.f;
            #pragma unroll
            for (int i = 0; i < 4; ++i) {
                float2 p = sStats[(sb + i) * 64 + e];
                ts += p.x; ts2 += p.y;
            }
            float mu  = ts * (1.f / 128.f);
            float var = ts2 * (1.f / 128.f) - mu * mu;
            float rs  = rsqrtf(var + EPSf);
            #pragma unroll
            for (int nf = 0; nf < 2; ++nf) {
                float y[4];
                #pragma unroll
                for (int j = 0; j < 4; ++j) {
                    float rsg = rs * g4[nf][j];
                    float f = fmaf(acc[nf][ef][j], rsg, fmaf(-mu, rsg, b4[nf][j]));
                    y[j] = f > 0.f ? f : 0.f;
                }
                int col = n0 + nf * 16 + kq * 4;
                int ch = col >> 3;
                uint2 pw; pw.x = pk2(y[0], y[1]); pw.y = pk2(y[2], y[3]);
                *(uint2*)(sY + e * 256 + ((ch ^ (e & 7)) << 3) + (col & 7)) = pw;
            }
        }
    }
    __syncthreads();

    // ---- q prefetch ----
    const int n0k = wv * 16;
    f32x4 qv[4];
    #pragma unroll
    for (int ef = 0; ef < 4; ++ef)
        qv[ef] = *(const f32x4*)(q + (size_t)dn[ef] * 128 + n0k + kq * 4);

    // ---- layer 2 (k) + logits: wave owns 16 cols ----
    float ps[4];
    {
        f32x4 a2[4];
        #pragma unroll
        for (int ef = 0; ef < 4; ++ef) a2[ef] = zf;
        for (int k0 = 0; k0 < 128; k0 += 32) {
            int cbase = (k0 >> 3) + kq;
            short8 wf2 = *(const short8*)(kW2t + (n0k + rA) * 128 + k0 + kq * 8);
            short8 yf[4];
            #pragma unroll
            for (int ef = 0; ef < 4; ++ef) {
                int r = ef * 16 + rA;
                yf[ef] = *(const short8*)(sY + r * 256 + ((cbase ^ (r & 7)) << 3));
            }
            #pragma unroll
            for (int ef = 0; ef < 4; ++ef)
                a2[ef] = __builtin_amdgcn_mfma_f32_16x16x32_bf16(wf2, yf[ef], a2[ef], 0, 0, 0);
        }
        f32x4 bb2 = *(const f32x4*)(kb2 + n0k + kq * 4);
        #pragma unroll
        for (int ef = 0; ef < 4; ++ef) {
            float s = 0.f;
            #pragma unroll
            for (int j = 0; j < 4; ++j) s += qv[ef][j] * (a2[ef][j] + bb2[j]);
            ps[ef] = s;
        }
        #pragma unroll
        for (int ef = 0; ef < 4; ++ef)
            ps[ef] += __shfl_xor(ps[ef], 16, 64);
    }
    __syncthreads();   // Y k-half reads done -> overlay sEX/sVl

    // ---- write sEX; layer 2 (v) on waves 0..3 ----
    {
        int h_base = wv * 2 + (kq >> 1);
        #pragma unroll
        for (int ef = 0; ef < 4; ++ef) {
            bool act = ((kq & 1) == 0) ? (ef < 2) : (ef >= 2);
            if (act) {
                int e = ef * 16 + rA;
                sEXat(sY, h_base * 64 + e) = __expf(ps[ef] * 0.35355339059327373f);
            }
        }
    }
    if (wv < 4) {
        f32x4 av = zf;
        int r = wv * 16 + rA;
        for (int k0 = 0; k0 < 128; k0 += 32) {
            int cbase = 16 + (k0 >> 3) + kq;
            short8 yv  = *(const short8*)(sY + r * 256 + ((cbase ^ (r & 7)) << 3));
            short8 wfv = *(const short8*)(vW2t + rA * 128 + k0 + kq * 8);
            av = __builtin_amdgcn_mfma_f32_16x16x32_bf16(wfv, yv, av, 0, 0, 0);
        }
        f32x4 bv = *(const f32x4*)(vb2 + kq * 4);
        #pragma unroll
        for (int j = 0; j < 4; ++j)
            sVLat(sY, (kq * 4 + j) * 64 + r) = av[j] + bv[j];
    }
    __syncthreads();

    // ---- segmented scan: 4 windows x 16 slots ----
    {
        const int s    = lane & 15;
        const int win  = wv & 3;
        const int slot = win * 16 + s;
        const int node = sDst[slot];

        bool fl = (s == 0) || (sDst[slot] != sDst[slot - 1]);
        unsigned long long bal = __ballot(fl);
        unsigned fb = (unsigned)((bal >> ((lane >> 4) * 16)) & 0xFFFFull);

        unsigned pre = fb & ((2u << s) - 1);
        int sstart = 31 - __clz(pre);

        float rx = sRel[slot * 3 + 0], ry = sRel[slot * 3 + 1], rz = sRel[slot * 3 + 2];
        int hg = (wv >> 2) * 8 + (lane >> 4) * 2;
        float ex2[2], px[2], py[2], pz[2];
        #pragma unroll
        for (int j = 0; j < 2; ++j) {
            int hh = hg + j;
            float exv = sEXat(sY, hh * 64 + slot);
            float vv  = sVLat(sY, hh * 64 + slot);
            float m = exv * vv;
            ex2[j] = exv; px[j] = m * rx; py[j] = m * ry; pz[j] = m * rz;
        }
        #pragma unroll
        for (int st = 1; st <= 8; st <<= 1) {
            bool take = (s - st >= sstart);
            #pragma unroll
            for (int j = 0; j < 2; ++j) {
                float t0 = __shfl_up(ex2[j], st, 16);
                float t1 = __shfl_up(px[j],  st, 16);
                float t2 = __shfl_up(py[j],  st, 16);
                float t3 = __shfl_up(pz[j],  st, 16);
                if (take) { ex2[j] += t0; px[j] += t1; py[j] += t2; pz[j] += t3; }
            }
        }
        bool isend = (s == 15) || ((fb >> (s + 1)) & 1u);
        if (isend) {
            #pragma unroll
            for (int j = 0; j < 2; ++j) {
                int hh = hg + j;
                atomicAdd(&Dg[node * 16 + hh], ex2[j]);
                atomicAdd(&Pg[node * 48 + 0 * 16 + hh], px[j]);
                atomicAdd(&Pg[node * 48 + 1 * 16 + hh], py[j]);
                atomicAdd(&Pg[node * 48 + 2 * 16 + hh], pz[j]);
            }
        }
    }
}

// ---------------------- finalize ----------------------
__global__ void k_fin(const float* __restrict__ Dg, const float* __restrict__ Pg,
                      float* __restrict__ out) {
    int n = blockIdx.x * 256 + threadIdx.x;
    if (n >= NN) return;
    float inv[16];
    #pragma unroll
    for (int hq = 0; hq < 4; ++hq) {
        f32x4 d = *(const f32x4*)(Dg + n * 16 + hq * 4);
        #pragma unroll
        for (int j = 0; j < 4; ++j) inv[hq * 4 + j] = (d[j] > 0.f) ? (1.f / d[j]) : 0.f;
    }
    #pragma unroll
    for (int c = 0; c < 3; ++c) {
        float s = 0.f;
        #pragma unroll
        for (int hq = 0; hq < 4; ++hq) {
            f32x4 p = *(const f32x4*)(Pg + n * 48 + c * 16 + hq * 4);
            #pragma unroll
            for (int j = 0; j < 4; ++j) s += p[j] * inv[hq * 4 + j];
        }
        out[n * 3 + c] = s * (1.f / 16.f);
    }
}

extern "C" void kernel_launch(void* const* d_in, const int* in_sizes, int n_in,
                              void* d_out, int out_size, void* d_ws, size_t ws_size,
                              hipStream_t stream) {
    const float* x   = (const float*)d_in[0];
    const float* h   = (const float*)d_in[1];
    const float* ea  = (const float*)d_in[2];
    const int*   ei  = (const int*)d_in[4];
    const float* kW1 = (const float*)d_in[5];
    const float* kb1 = (const float*)d_in[6];
    const float* kg  = (const float*)d_in[7];
    const float* kbt = (const float*)d_in[8];
    const float* kW2 = (const float*)d_in[9];
    const float* kb2 = (const float*)d_in[10];
    const float* vW1 = (const float*)d_in[11];
    const float* vb1 = (const float*)d_in[12];
    const float* vg  = (const float*)d_in[13];
    const float* vbt = (const float*)d_in[14];
    const float* vW2 = (const float*)d_in[15];
    const float* vb2 = (const float*)d_in[16];
    const float* qW1 = (const float*)d_in[17];
    const float* qb1 = (const float*)d_in[18];
    const float* qg  = (const float*)d_in[19];
    const float* qbt = (const float*)d_in[20];
    const float* qW2 = (const float*)d_in[21];
    const float* qb2 = (const float*)d_in[22];

    float* ws = (float*)d_ws;
    float* qbuf = ws;                              // 0 .. 1,280,000
    float* Dg   = ws + 1280000;                    // N*16
    float* Pg   = ws + 1440000;                    // N*48 (contiguous with Dg)
    float* cdst = ws + 1920000;                    // N*256 f32 -> 4,480,000
    unsigned short* csrc_bf = (unsigned short*)(ws + 4480000);  // N*256 halves = 1,280,000 w -> 5,760,000
    unsigned short* h_bf = (unsigned short*)(ws + 5760000);     // N*128 halves (640,000 w) -> 6,400,000
    unsigned short* Wt1  = (unsigned short*)(ws + 6400000);     // 45,056 w -> 6,445,056
    unsigned short* kW2t = (unsigned short*)(ws + 6445056);     // 8,192 w -> 6,453,248
    unsigned short* vW2t = (unsigned short*)(ws + 6453248);     // 1,024 w -> 6,454,272
    unsigned short* qW1t = (unsigned short*)(ws + 6454272);     // 8,192 w -> 6,462,464
    unsigned short* qW2t = (unsigned short*)(ws + 6462464);     // 8,192 w -> 6,470,656
    int* cnt  = (int*)(ws + 6470656);              // N -> 6,480,656
    int* cnt2 = (int*)(ws + 6480656);              // N -> 6,490,656
    float* edata2 = ws + 6490656;                  // E*8 = 2,560,000 w -> 9,050,656
    unsigned short* featbf = (unsigned short*)(ws + 9050656);   // E*80 halves = 12,800,000 w
    float* out = (float*)d_out;

    hipMemsetAsync(cnt, 0, NN * sizeof(int), stream);
    hipMemsetAsync(Dg, 0, NN * 64 * sizeof(float), stream);   // Dg + Pg contiguous
    hipLaunchKernelGGL(k_pre,   dim3(PRE_HIST + PRE_PREP), dim3(256), 0, stream,
                       ei, cnt, h, kW1, vW1, kW2, vW2, qW1, qW2,
                       h_bf, Wt1, kW2t, vW2t, qW1t, qW2t);
    hipLaunchKernelGGL(k_scan,  dim3(1),    dim3(1024), 0, stream, cnt, cnt2);
    hipLaunchKernelGGL(k_placeq, dim3(PQ_PLACE + PQ_QMLP + PQ_CPREP), dim3(256), 0, stream,
                       ei, cnt2, x, ea, edata2, featbf, h_bf, Wt1, kb1, vb1,
                       qW1t, qb1, qg, qbt, qW2t, qb2, qbuf, cdst, csrc_bf);
    hipLaunchKernelGGL(k_edge,  dim3(5000), dim3(512),  0, stream,
                       edata2, featbf, Wt1, cdst, csrc_bf,
                       kg, kbt, vg, vbt,
                       kW2t, kb2, vW2t, vb2,
                       qbuf, Dg, Pg);
    hipLaunchKernelGGL(k_fin,   dim3(40),   dim3(256),  0, stream, Dg, Pg, out);
}

// Round 14
// 220.151 us; speedup vs baseline: 1.0334x; 1.0334x over previous
//
#include <hip/hip_runtime.h>
#include <hip/hip_bf16.h>
#include <math.h>

typedef __attribute__((ext_vector_type(8))) short short8;
typedef __attribute__((ext_vector_type(4))) float f32x4;

#define NN 10000
#define EE 320000
#define NHEAD 16
#define EPSf 1e-5f

// ---------- bf16 helpers ----------
__device__ __forceinline__ unsigned short f2bf(float f) {
    union { float f; unsigned u; } v; v.f = f;
    unsigned u = v.u;
    u += 0x7fffu + ((u >> 16) & 1u);   // RNE
    return (unsigned short)(u >> 16);
}
__device__ __forceinline__ unsigned pk2(float a, float b) {
    __hip_bfloat162 t = __float22bfloat162_rn(make_float2(a, b));
    return *reinterpret_cast<unsigned*>(&t);
}
__device__ __forceinline__ float bfLo(unsigned u) { return __uint_as_float(u << 16); }
__device__ __forceinline__ float bfHi(unsigned u) { return __uint_as_float(u & 0xFFFF0000u); }

// sEX/sVl overlays on Y's k-half byte region (rows 0..15 / 16..31)
__device__ __forceinline__ float& sEXat(unsigned short* sR, int ix) {
    return *(float*)(sR + ((ix >> 6) << 8) + ((ix & 63) << 1));
}
__device__ __forceinline__ float& sVLat(unsigned short* sR, int ix) {
    return *(float*)(sR + 4096 + ((ix >> 6) << 8) + ((ix & 63) << 1));
}

// ed-tile slot: 12 chunks/row, XOR swizzle within aligned groups (8 + 4)
__device__ __forceinline__ int edslot(int r, int cl) {
    int c = (cl < 8) ? (cl ^ (r & 7)) : (8 + ((cl & 3) ^ (r & 3)));
    return r * 96 + (c << 3);
}

// ---------- fused: hist (1250) + prep (1802) ----------
// Wt1 ed-block k' order: [ea(4) | gauss(80) | zeros(12)] at k' 256..351
#define PRE_HIST 1250
#define PRE_PREP 1802
__global__ __launch_bounds__(256) void k_pre(
    const int* __restrict__ ei, int* __restrict__ cnt,
    const float* __restrict__ h,
    const float* __restrict__ kW1, const float* __restrict__ vW1,
    const float* __restrict__ kW2, const float* __restrict__ vW2,
    const float* __restrict__ qW1, const float* __restrict__ qW2,
    unsigned short* __restrict__ h_bf, unsigned short* __restrict__ Wt1,
    unsigned short* __restrict__ kW2t, unsigned short* __restrict__ vW2t,
    unsigned short* __restrict__ qW1t, unsigned short* __restrict__ qW2t)
{
    const int tid = threadIdx.x;
    int b = blockIdx.x;

    if (b < PRE_HIST) {                       // ---- histogram ----
        int e = b * 256 + tid;                // EE = 1250*256 exactly
        atomicAdd(&cnt[ei[EE + e]], 1);
        return;
    }
    b -= PRE_HIST;                            // ---- prep ----
    int i = b * 256 + tid;
    if (i < 320000) {                         // h: 4 elements per thread
        float4 v = *(const float4*)(h + i * 4);
        uint2 o; o.x = pk2(v.x, v.y); o.y = pk2(v.z, v.w);
        *(uint2*)(h_bf + i * 4) = o;
        return;
    }
    int j = i - 320000;
    if (j < 256 * 352) {
        int n = j / 352, k = j % 352;
        float val = 0.f;
        int pk = -1;
        if (k < 128)      pk = 84 + k;            // h_dst
        else if (k < 256) pk = 212 + (k - 128);   // h_src
        else if (k < 260) pk = k - 256;           // ea
        else if (k < 340) pk = 4 + (k - 260);     // gauss
        if (pk >= 0)
            val = (n < 128) ? kW1[pk * 128 + n] : vW1[pk * 128 + (n - 128)];
        Wt1[j] = f2bf(val); return;
    }
    j -= 256 * 352;
    if (j < 128 * 128) { int n = j >> 7, k = j & 127; kW2t[j] = f2bf(kW2[k * 128 + n]); return; }
    j -= 128 * 128;
    if (j < 16 * 128)  { int n = j >> 7, k = j & 127; vW2t[j] = f2bf(vW2[k * 16 + n]); return; }
    j -= 16 * 128;
    if (j < 128 * 128) { int n = j >> 7, k = j & 127; qW1t[j] = f2bf(qW1[k * 128 + n]); return; }
    j -= 128 * 128;
    if (j < 128 * 128) { int n = j >> 7, k = j & 127; qW2t[j] = f2bf(qW2[k * 128 + n]); return; }
}

// ---------------------- scan (wave-based) ----------------------
__global__ __launch_bounds__(1024) void k_scan(const int* __restrict__ cnt,
                                               int* __restrict__ cnt2) {
    __shared__ int wsum[16];
    const int t = threadIdx.x;
    const int lane = t & 63, w = t >> 6;
    int loc[10];
    int s = 0;
    #pragma unroll
    for (int i = 0; i < 10; ++i) {
        int idx = t * 10 + i;
        loc[i] = (idx < NN) ? cnt[idx] : 0;
        s += loc[i];
    }
    int sc = s;
    #pragma unroll
    for (int off = 1; off < 64; off <<= 1) {
        int v = __shfl_up(sc, off, 64);
        if (lane >= off) sc += v;
    }
    if (lane == 63) wsum[w] = sc;
    __syncthreads();
    if (w == 0) {
        int v = (lane < 16) ? wsum[lane] : 0;
        int c = v;
        #pragma unroll
        for (int off = 1; off < 16; off <<= 1) {
            int t2 = __shfl_up(c, off, 64);
            if (lane >= off) c += t2;
        }
        if (lane < 16) wsum[lane] = c - v;
    }
    __syncthreads();
    int run = wsum[w] + sc - s;
    #pragma unroll
    for (int i = 0; i < 10; ++i) {
        int idx = t * 10 + i;
        if (idx < NN) { cnt2[idx] = run; run += loc[i]; }
    }
}

// ---- fused: place+edata (1250) + q-MLP (157) + c-table precompute (157) ----
#define PQ_PLACE 1250
#define PQ_QMLP  157
#define PQ_CPREP 157
__global__ __launch_bounds__(256) void k_placeq(
    const int* __restrict__ ei, int* __restrict__ cnt2,
    const float* __restrict__ x, const float* __restrict__ ea,
    float* __restrict__ edata2,
    const unsigned short* __restrict__ h_bf,
    const unsigned short* __restrict__ Wt1,
    const float* __restrict__ kb1, const float* __restrict__ vb1,
    const unsigned short* __restrict__ qW1t, const float* __restrict__ qb1,
    const float* __restrict__ qg,  const float* __restrict__ qbt,
    const unsigned short* __restrict__ qW2t, const float* __restrict__ qb2,
    float* __restrict__ qout,
    float* __restrict__ cdst, unsigned short* __restrict__ csrc_bf)
{
    __shared__ __align__(16) unsigned short sQ[64 * 128];
    __shared__ float2 sSt[4 * 64];
    const int tid = threadIdx.x;
    int b = blockIdx.x;

    if (b < PQ_PLACE) {                       // ---- place + edata2 pack ----
        int e = b * 256 + tid;
        int s = ei[e], d = ei[EE + e];
        int slot = atomicAdd(&cnt2[d], 1);
        float rx = x[d*3+0] - x[s*3+0];
        float ry = x[d*3+1] - x[s*3+1];
        float rz = x[d*3+2] - x[s*3+2];
        float dist = sqrtf(rx*rx + ry*ry + rz*rz);
        float4 eav = *(const float4*)(ea + e * 4);
        float* ep = edata2 + (size_t)slot * 8;
        ep[0] = rx; ep[1] = ry; ep[2] = rz; ep[3] = dist;
        unsigned* epu = (unsigned*)ep;
        epu[4] = pk2(eav.x, eav.y);
        epu[5] = pk2(eav.z, eav.w);
        ((int*)ep)[6] = s; ((int*)ep)[7] = d;
        return;
    }
    b -= PQ_PLACE;
    const int lane = tid & 63, wv = tid >> 6, rA = lane & 15, kq = lane >> 4;
    f32x4 zf = {0.f, 0.f, 0.f, 0.f};

    if (b >= PQ_QMLP) {                       // ---- c-table precompute ----
        b -= PQ_QMLP;
        const int n0c = b * 64;
        #pragma unroll
        for (int it = 0; it < 4; ++it) {
            int p = tid + it * 256;
            int r = p >> 4, c = p & 15;
            int node = n0c + r; if (node >= NN) node = NN - 1;
            uint4 v = *(const uint4*)(h_bf + node * 128 + c * 8);
            *(uint4*)(sQ + r * 128 + ((c ^ (r & 7)) << 3)) = v;
        }
        __syncthreads();
        const int n0w = wv * 64;              // 4 waves x 64 cols
        #pragma unroll
        for (int T = 0; T < 2; ++T) {
            const int Toff = T << 7;
            f32x4 a[4][4];
            #pragma unroll
            for (int nf = 0; nf < 4; ++nf)
                #pragma unroll
                for (int ef = 0; ef < 4; ++ef) a[nf][ef] = zf;
            for (int k0 = 0; k0 < 128; k0 += 32) {
                int cb = (k0 >> 3) + kq;
                short8 wf[4], kv[4];
                #pragma unroll
                for (int nf = 0; nf < 4; ++nf)
                    wf[nf] = *(const short8*)(Wt1 + (n0w + nf * 16 + rA) * 352 + Toff + k0 + kq * 8);
                #pragma unroll
                for (int ef = 0; ef < 4; ++ef) {
                    int r = ef * 16 + rA;
                    kv[ef] = *(const short8*)(sQ + r * 128 + ((cb ^ (r & 7)) << 3));
                }
                #pragma unroll
                for (int nf = 0; nf < 4; ++nf)
                    #pragma unroll
                    for (int ef = 0; ef < 4; ++ef)
                        a[nf][ef] = __builtin_amdgcn_mfma_f32_16x16x32_bf16(wf[nf], kv[ef], a[nf][ef], 0, 0, 0);
            }
            if (T == 0) {
                #pragma unroll
                for (int nf = 0; nf < 4; ++nf) {
                    int col = n0w + nf * 16 + kq * 4;
                    f32x4 bb = (col < 128) ? *(const f32x4*)(kb1 + col)
                                           : *(const f32x4*)(vb1 + col - 128);
                    #pragma unroll
                    for (int ef = 0; ef < 4; ++ef) {
                        int node = n0c + ef * 16 + rA;
                        if (node < NN) {
                            f32x4 o;
                            #pragma unroll
                            for (int j = 0; j < 4; ++j) o[j] = a[nf][ef][j] + bb[j];
                            *(f32x4*)(cdst + (size_t)node * 256 + col) = o;
                        }
                    }
                }
            } else {
                #pragma unroll
                for (int nf = 0; nf < 4; ++nf) {
                    int col = n0w + nf * 16 + kq * 4;
                    #pragma unroll
                    for (int ef = 0; ef < 4; ++ef) {
                        int node = n0c + ef * 16 + rA;
                        if (node < NN) {
                            uint2 pw;
                            pw.x = pk2(a[nf][ef][0], a[nf][ef][1]);
                            pw.y = pk2(a[nf][ef][2], a[nf][ef][3]);
                            *(uint2*)(csrc_bf + (size_t)node * 256 + col) = pw;
                        }
                    }
                }
            }
        }
        return;
    }
    // ---- q-MLP (MFMA) ----
    const int n0q = b * 64;
    #pragma unroll
    for (int it = 0; it < 4; ++it) {
        int p = tid + it * 256;
        int r = p >> 4, c = p & 15;
        int node = n0q + r; if (node >= NN) node = NN - 1;
        uint4 v = *(const uint4*)(h_bf + node * 128 + c * 8);
        *(uint4*)(sQ + r * 128 + ((c ^ (r & 7)) << 3)) = v;
    }
    __syncthreads();

    const int nb = wv * 32;
    f32x4 acc[2][4];
    #pragma unroll
    for (int nf = 0; nf < 2; ++nf)
        #pragma unroll
        for (int ef = 0; ef < 4; ++ef) acc[nf][ef] = zf;

    for (int k0 = 0; k0 < 128; k0 += 32) {
        int cb = (k0 >> 3) + kq;
        short8 wf[2], kv[4];
        #pragma unroll
        for (int nf = 0; nf < 2; ++nf)
            wf[nf] = *(const short8*)(qW1t + (nb + nf * 16 + rA) * 128 + k0 + kq * 8);
        #pragma unroll
        for (int ef = 0; ef < 4; ++ef) {
            int r = ef * 16 + rA;
            kv[ef] = *(const short8*)(sQ + r * 128 + ((cb ^ (r & 7)) << 3));
        }
        #pragma unroll
        for (int nf = 0; nf < 2; ++nf)
            #pragma unroll
            for (int ef = 0; ef < 4; ++ef)
                acc[nf][ef] = __builtin_amdgcn_mfma_f32_16x16x32_bf16(wf[nf], kv[ef], acc[nf][ef], 0, 0, 0);
    }
    #pragma unroll
    for (int nf = 0; nf < 2; ++nf) {
        f32x4 bb = *(const f32x4*)(qb1 + nb + nf * 16 + kq * 4);
        #pragma unroll
        for (int ef = 0; ef < 4; ++ef)
            #pragma unroll
            for (int j = 0; j < 4; ++j) acc[nf][ef][j] += bb[j];
    }
    float sm[4], sq2[4];
    #pragma unroll
    for (int ef = 0; ef < 4; ++ef) {
        float s = 0.f, s2 = 0.f;
        #pragma unroll
        for (int nf = 0; nf < 2; ++nf)
            #pragma unroll
            for (int j = 0; j < 4; ++j) { float v = acc[nf][ef][j]; s += v; s2 += v * v; }
        s  += __shfl_xor(s, 16, 64);  s  += __shfl_xor(s, 32, 64);
        s2 += __shfl_xor(s2, 16, 64); s2 += __shfl_xor(s2, 32, 64);
        sm[ef] = s; sq2[ef] = s2;
    }
    if (kq == 0) {
        #pragma unroll
        for (int ef = 0; ef < 4; ++ef)
            sSt[wv * 64 + ef * 16 + rA] = make_float2(sm[ef], sq2[ef]);
    }
    __syncthreads();

    {
        f32x4 g4[2], b4[2];
        #pragma unroll
        for (int nf = 0; nf < 2; ++nf) {
            g4[nf] = *(const f32x4*)(qg  + nb + nf * 16 + kq * 4);
            b4[nf] = *(const f32x4*)(qbt + nb + nf * 16 + kq * 4);
        }
        #pragma unroll
        for (int ef = 0; ef < 4; ++ef) {
            int r = ef * 16 + rA;
            float ts = 0.f, ts2 = 0.f;
            #pragma unroll
            for (int w2 = 0; w2 < 4; ++w2) {
                float2 p = sSt[w2 * 64 + r];
                ts += p.x; ts2 += p.y;
            }
            float mu  = ts * (1.f / 128.f);
            float var = ts2 * (1.f / 128.f) - mu * mu;
            float rs  = rsqrtf(var + EPSf);
            #pragma unroll
            for (int nf = 0; nf < 2; ++nf) {
                float y[4];
                #pragma unroll
                for (int j = 0; j < 4; ++j) {
                    float f = (acc[nf][ef][j] - mu) * rs * g4[nf][j] + b4[nf][j];
                    y[j] = f > 0.f ? f : 0.f;
                }
                int col = nb + nf * 16 + kq * 4;
                int ch = col >> 3;
                uint2 pw; pw.x = pk2(y[0], y[1]); pw.y = pk2(y[2], y[3]);
                *(uint2*)(sQ + r * 128 + ((ch ^ (r & 7)) << 3) + (col & 7)) = pw;
            }
        }
    }
    __syncthreads();

    f32x4 a2[2][4];
    #pragma unroll
    for (int nf = 0; nf < 2; ++nf)
        #pragma unroll
        for (int ef = 0; ef < 4; ++ef) a2[nf][ef] = zf;
    for (int k0 = 0; k0 < 128; k0 += 32) {
        int cb = (k0 >> 3) + kq;
        short8 wf[2], yv[4];
        #pragma unroll
        for (int nf = 0; nf < 2; ++nf)
            wf[nf] = *(const short8*)(qW2t + (nb + nf * 16 + rA) * 128 + k0 + kq * 8);
        #pragma unroll
        for (int ef = 0; ef < 4; ++ef) {
            int r = ef * 16 + rA;
            yv[ef] = *(const short8*)(sQ + r * 128 + ((cb ^ (r & 7)) << 3));
        }
        #pragma unroll
        for (int nf = 0; nf < 2; ++nf)
            #pragma unroll
            for (int ef = 0; ef < 4; ++ef)
                a2[nf][ef] = __builtin_amdgcn_mfma_f32_16x16x32_bf16(wf[nf], yv[ef], a2[nf][ef], 0, 0, 0);
    }
    #pragma unroll
    for (int nf = 0; nf < 2; ++nf) {
        f32x4 bb = *(const f32x4*)(qb2 + nb + nf * 16 + kq * 4);
        #pragma unroll
        for (int ef = 0; ef < 4; ++ef) {
            int node = n0q + ef * 16 + rA;
            if (node < NN) {
                f32x4 o;
                #pragma unroll
                for (int j = 0; j < 4; ++j) o[j] = a2[nf][ef][j] + bb[j];
                *(f32x4*)(qout + node * 128 + nb + nf * 16 + kq * 4) = o;
            }
        }
    }
}

// ------- per-slot kernel: pre-issued gathers, direct-global ed staging, K=96 MFMA -------
__global__ __launch_bounds__(512) void k_edge(
    const float* __restrict__ edata2,
    const unsigned short* __restrict__ Wt1,
    const float* __restrict__ cdst, const unsigned short* __restrict__ csrc_bf,
    const float* __restrict__ kg, const float* __restrict__ kbt,
    const float* __restrict__ vg, const float* __restrict__ vbt,
    const unsigned short* __restrict__ kW2t, const float* __restrict__ kb2,
    const unsigned short* __restrict__ vW2t, const float* __restrict__ vb2,
    const float* __restrict__ q,
    float* __restrict__ Dg, float* __restrict__ Pg)
{
    // sY (32KB) time-multiplexed: ed tile [64][96] -> Y [64][256] -> EX/V overlay.
    __shared__ __align__(16) unsigned short sY[64 * 256];
    __shared__ float2 sStats[8 * 64];
    __shared__ float sRel[64 * 3];
    __shared__ int   sSrc[64], sDst[64];
    unsigned short* sED = sY;   // alias (layout per edslot)

    const int tid  = threadIdx.x;
    const int e0   = blockIdx.x * 64;
    const int lane = tid & 63;
    const int wv   = tid >> 6;          // 0..7
    const int rA   = lane & 15;
    const int kq   = lane >> 4;

    // ---- prologue (scan data only; consumed after later barriers) ----
    if (tid < 64) {
        const float* ep = edata2 + (size_t)(e0 + tid) * 8;
        f32x4 w0 = *(const f32x4*)ep;
        int2  sd = *(const int2*)((const int*)ep + 6);
        sRel[tid*3+0] = w0[0]; sRel[tid*3+1] = w0[1]; sRel[tid*3+2] = w0[2];
        sSrc[tid] = sd.x; sDst[tid] = sd.y;
    }

    // ---- per-thread src/dst + pre-issued c-gather loads ----
    const int n0 = wv * 32;
    int dn[4], sn[4];
    #pragma unroll
    for (int ef = 0; ef < 4; ++ef) {
        int2 sd = *(const int2*)((const int*)edata2 + (size_t)(e0 + ef * 16 + rA) * 8 + 6);
        sn[ef] = sd.x; dn[ef] = sd.y;
    }
    f32x4 cdv[2][4];
    uint2 csv[2][4];
    #pragma unroll
    for (int ef = 0; ef < 4; ++ef)
        #pragma unroll
        for (int nf = 0; nf < 2; ++nf) {
            cdv[nf][ef] = *(const f32x4*)(cdst + (size_t)dn[ef] * 256 + n0 + nf * 16 + kq * 4);
            csv[nf][ef] = *(const uint2*)(csrc_bf + (size_t)sn[ef] * 256 + n0 + nf * 16 + kq * 4);
        }

    // ---- stage ed features (dist/ea read direct from edata2; no prologue barrier) ----
    const float step  = 10.0f / 19.0f;
    const float coeff = -0.5f / (step * step);
    #pragma unroll
    for (int it = 0; it < 2; ++it) {
        int p = tid + it * 512;
        if (p < 768) {
            int r = (p * 5462) >> 16;        // p / 12
            int cl = p - r * 12;
            const float* ep = edata2 + (size_t)(e0 + r) * 8;
            float dist = ep[3];
            uint2 eap = *(const uint2*)((const unsigned*)ep + 4);
            float eaf[4] = { bfLo(eap.x), bfHi(eap.x), bfLo(eap.y), bfHi(eap.y) };
            int i0 = cl * 8;
            float v[8];
            #pragma unroll
            for (int j = 0; j < 8; ++j) {
                int i = i0 + j;
                float val;
                if (i < 4) val = eaf[i];
                else if (i < 84) {
                    int im4 = i - 4;
                    int f = (im4 * 3277) >> 16;   // im4 / 20
                    int gg = im4 - f * 20;
                    float dd = dist - (float)gg * step;
                    val = eaf[f] * __expf(coeff * dd * dd);
                } else val = 0.f;
                v[j] = val;
            }
            uint4 pw;
            pw.x = pk2(v[0], v[1]); pw.y = pk2(v[2], v[3]);
            pw.z = pk2(v[4], v[5]); pw.w = pk2(v[6], v[7]);
            *(uint4*)(sED + edslot(r, cl)) = pw;
        }
    }
    __syncthreads();

    // ---- seed acc (gather loads drained under staging) ----
    f32x4 zf = {0.f, 0.f, 0.f, 0.f};
    f32x4 acc[2][4];
    #pragma unroll
    for (int ef = 0; ef < 4; ++ef)
        #pragma unroll
        for (int nf = 0; nf < 2; ++nf) {
            f32x4 cs;
            cs[0] = bfLo(csv[nf][ef].x);
            cs[1] = bfHi(csv[nf][ef].x);
            cs[2] = bfLo(csv[nf][ef].y);
            cs[3] = bfHi(csv[nf][ef].y);
            acc[nf][ef] = cdv[nf][ef] + cs;
        }

    // ---- ed MFMA: K = 96 (weights at Wt1 k' 256..351) ----
    #pragma unroll
    for (int s = 0; s < 3; ++s) {
        int k0 = s * 32;
        short8 wfr[2], kv[4];
        #pragma unroll
        for (int nf = 0; nf < 2; ++nf)
            wfr[nf] = *(const short8*)(Wt1 + (n0 + nf * 16 + rA) * 352 + 256 + k0 + kq * 8);
        #pragma unroll
        for (int ef = 0; ef < 4; ++ef) {
            int r = ef * 16 + rA;
            kv[ef] = *(const short8*)(sED + edslot(r, s * 4 + kq));
        }
        #pragma unroll
        for (int nf = 0; nf < 2; ++nf)
            #pragma unroll
            for (int ef = 0; ef < 4; ++ef)
                acc[nf][ef] = __builtin_amdgcn_mfma_f32_16x16x32_bf16(wfr[nf], kv[ef], acc[nf][ef], 0, 0, 0);
    }

    // ---- in-register LN stats ----
    float sm[4], sq2[4];
    #pragma unroll
    for (int ef = 0; ef < 4; ++ef) {
        float s = 0.f, s2 = 0.f;
        #pragma unroll
        for (int nf = 0; nf < 2; ++nf)
            #pragma unroll
            for (int j = 0; j < 4; ++j) { float v = acc[nf][ef][j]; s += v; s2 += v * v; }
        s  += __shfl_xor(s, 16, 64);  s  += __shfl_xor(s, 32, 64);
        s2 += __shfl_xor(s2, 16, 64); s2 += __shfl_xor(s2, 32, 64);
        sm[ef] = s; sq2[ef] = s2;
    }
    if (kq == 0) {
        #pragma unroll
        for (int ef = 0; ef < 4; ++ef)
            sStats[wv * 64 + ef * 16 + rA] = make_float2(sm[ef], sq2[ef]);
    }
    __syncthreads();   // stats ready; separates sED reads from sY writes

    // ---- normalize + ReLU + pack -> Y ----
    {
        const float* gp = (wv < 4) ? kg : vg;
        const float* bp = (wv < 4) ? kbt : vbt;
        const int sb = (wv < 4) ? 0 : 4;
        f32x4 g4[2], b4[2];
        #pragma unroll
        for (int nf = 0; nf < 2; ++nf) {
            int cl = (wv & 3) * 32 + nf * 16 + kq * 4;
            g4[nf] = *(const f32x4*)(gp + cl);
            b4[nf] = *(const f32x4*)(bp + cl);
        }
        #pragma unroll
        for (int ef = 0; ef < 4; ++ef) {
            int e = ef * 16 + rA;
            float ts = 0.f, ts2 = 0.f;
            #pragma unroll
            for (int i = 0; i < 4; ++i) {
                float2 p = sStats[(sb + i) * 64 + e];
                ts += p.x; ts2 += p.y;
            }
            float mu  = ts * (1.f / 128.f);
            float var = ts2 * (1.f / 128.f) - mu * mu;
            float rs  = rsqrtf(var + EPSf);
            #pragma unroll
            for (int nf = 0; nf < 2; ++nf) {
                float y[4];
                #pragma unroll
                for (int j = 0; j < 4; ++j) {
                    float rsg = rs * g4[nf][j];
                    float f = fmaf(acc[nf][ef][j], rsg, fmaf(-mu, rsg, b4[nf][j]));
                    y[j] = f > 0.f ? f : 0.f;
                }
                int col = n0 + nf * 16 + kq * 4;
                int ch = col >> 3;
                uint2 pw; pw.x = pk2(y[0], y[1]); pw.y = pk2(y[2], y[3]);
                *(uint2*)(sY + e * 256 + ((ch ^ (e & 7)) << 3) + (col & 7)) = pw;
            }
        }
    }
    __syncthreads();

    // ---- q prefetch ----
    const int n0k = wv * 16;
    f32x4 qv[4];
    #pragma unroll
    for (int ef = 0; ef < 4; ++ef)
        qv[ef] = *(const f32x4*)(q + (size_t)dn[ef] * 128 + n0k + kq * 4);

    // ---- layer 2 (k) + logits: wave owns 16 cols ----
    float ps[4];
    {
        f32x4 a2[4];
        #pragma unroll
        for (int ef = 0; ef < 4; ++ef) a2[ef] = zf;
        for (int k0 = 0; k0 < 128; k0 += 32) {
            int cbase = (k0 >> 3) + kq;
            short8 wf2 = *(const short8*)(kW2t + (n0k + rA) * 128 + k0 + kq * 8);
            short8 yf[4];
            #pragma unroll
            for (int ef = 0; ef < 4; ++ef) {
                int r = ef * 16 + rA;
                yf[ef] = *(const short8*)(sY + r * 256 + ((cbase ^ (r & 7)) << 3));
            }
            #pragma unroll
            for (int ef = 0; ef < 4; ++ef)
                a2[ef] = __builtin_amdgcn_mfma_f32_16x16x32_bf16(wf2, yf[ef], a2[ef], 0, 0, 0);
        }
        f32x4 bb2 = *(const f32x4*)(kb2 + n0k + kq * 4);
        #pragma unroll
        for (int ef = 0; ef < 4; ++ef) {
            float s = 0.f;
            #pragma unroll
            for (int j = 0; j < 4; ++j) s += qv[ef][j] * (a2[ef][j] + bb2[j]);
            ps[ef] = s;
        }
        #pragma unroll
        for (int ef = 0; ef < 4; ++ef)
            ps[ef] += __shfl_xor(ps[ef], 16, 64);
    }
    __syncthreads();   // Y k-half reads done -> overlay sEX/sVl

    // ---- write sEX; layer 2 (v) on waves 0..3 ----
    {
        int h_base = wv * 2 + (kq >> 1);
        #pragma unroll
        for (int ef = 0; ef < 4; ++ef) {
            bool act = ((kq & 1) == 0) ? (ef < 2) : (ef >= 2);
            if (act) {
                int e = ef * 16 + rA;
                sEXat(sY, h_base * 64 + e) = __expf(ps[ef] * 0.35355339059327373f);
            }
        }
    }
    if (wv < 4) {
        f32x4 av = zf;
        int r = wv * 16 + rA;
        for (int k0 = 0; k0 < 128; k0 += 32) {
            int cbase = 16 + (k0 >> 3) + kq;
            short8 yv  = *(const short8*)(sY + r * 256 + ((cbase ^ (r & 7)) << 3));
            short8 wfv = *(const short8*)(vW2t + rA * 128 + k0 + kq * 8);
            av = __builtin_amdgcn_mfma_f32_16x16x32_bf16(wfv, yv, av, 0, 0, 0);
        }
        f32x4 bv = *(const f32x4*)(vb2 + kq * 4);
        #pragma unroll
        for (int j = 0; j < 4; ++j)
            sVLat(sY, (kq * 4 + j) * 64 + r) = av[j] + bv[j];
    }
    __syncthreads();

    // ---- segmented scan: 4 windows x 16 slots ----
    {
        const int s    = lane & 15;
        const int win  = wv & 3;
        const int slot = win * 16 + s;
        const int node = sDst[slot];

        bool fl = (s == 0) || (sDst[slot] != sDst[slot - 1]);
        unsigned long long bal = __ballot(fl);
        unsigned fb = (unsigned)((bal >> ((lane >> 4) * 16)) & 0xFFFFull);

        unsigned pre = fb & ((2u << s) - 1);
        int sstart = 31 - __clz(pre);

        float rx = sRel[slot * 3 + 0], ry = sRel[slot * 3 + 1], rz = sRel[slot * 3 + 2];
        int hg = (wv >> 2) * 8 + (lane >> 4) * 2;
        float ex2[2], px[2], py[2], pz[2];
        #pragma unroll
        for (int j = 0; j < 2; ++j) {
            int hh = hg + j;
            float exv = sEXat(sY, hh * 64 + slot);
            float vv  = sVLat(sY, hh * 64 + slot);
            float m = exv * vv;
            ex2[j] = exv; px[j] = m * rx; py[j] = m * ry; pz[j] = m * rz;
        }
        #pragma unroll
        for (int st = 1; st <= 8; st <<= 1) {
            bool take = (s - st >= sstart);
            #pragma unroll
            for (int j = 0; j < 2; ++j) {
                float t0 = __shfl_up(ex2[j], st, 16);
                float t1 = __shfl_up(px[j],  st, 16);
                float t2 = __shfl_up(py[j],  st, 16);
                float t3 = __shfl_up(pz[j],  st, 16);
                if (take) { ex2[j] += t0; px[j] += t1; py[j] += t2; pz[j] += t3; }
            }
        }
        bool isend = (s == 15) || ((fb >> (s + 1)) & 1u);
        if (isend) {
            #pragma unroll
            for (int j = 0; j < 2; ++j) {
                int hh = hg + j;
                atomicAdd(&Dg[node * 16 + hh], ex2[j]);
                atomicAdd(&Pg[node * 48 + 0 * 16 + hh], px[j]);
                atomicAdd(&Pg[node * 48 + 1 * 16 + hh], py[j]);
                atomicAdd(&Pg[node * 48 + 2 * 16 + hh], pz[j]);
            }
        }
    }
}

// ---------------------- finalize ----------------------
__global__ void k_fin(const float* __restrict__ Dg, const float* __restrict__ Pg,
                      float* __restrict__ out) {
    int n = blockIdx.x * 256 + threadIdx.x;
    if (n >= NN) return;
    float inv[16];
    #pragma unroll
    for (int hq = 0; hq < 4; ++hq) {
        f32x4 d = *(const f32x4*)(Dg + n * 16 + hq * 4);
        #pragma unroll
        for (int j = 0; j < 4; ++j) inv[hq * 4 + j] = (d[j] > 0.f) ? (1.f / d[j]) : 0.f;
    }
    #pragma unroll
    for (int c = 0; c < 3; ++c) {
        float s = 0.f;
        #pragma unroll
        for (int hq = 0; hq < 4; ++hq) {
            f32x4 p = *(const f32x4*)(Pg + n * 48 + c * 16 + hq * 4);
            #pragma unroll
            for (int j = 0; j < 4; ++j) s += p[j] * inv[hq * 4 + j];
        }
        out[n * 3 + c] = s * (1.f / 16.f);
    }
}

extern "C" void kernel_launch(void* const* d_in, const int* in_sizes, int n_in,
                              void* d_out, int out_size, void* d_ws, size_t ws_size,
                              hipStream_t stream) {
    const float* x   = (const float*)d_in[0];
    const float* h   = (const float*)d_in[1];
    const float* ea  = (const float*)d_in[2];
    const int*   ei  = (const int*)d_in[4];
    const float* kW1 = (const float*)d_in[5];
    const float* kb1 = (const float*)d_in[6];
    const float* kg  = (const float*)d_in[7];
    const float* kbt = (const float*)d_in[8];
    const float* kW2 = (const float*)d_in[9];
    const float* kb2 = (const float*)d_in[10];
    const float* vW1 = (const float*)d_in[11];
    const float* vb1 = (const float*)d_in[12];
    const float* vg  = (const float*)d_in[13];
    const float* vbt = (const float*)d_in[14];
    const float* vW2 = (const float*)d_in[15];
    const float* vb2 = (const float*)d_in[16];
    const float* qW1 = (const float*)d_in[17];
    const float* qb1 = (const float*)d_in[18];
    const float* qg  = (const float*)d_in[19];
    const float* qbt = (const float*)d_in[20];
    const float* qW2 = (const float*)d_in[21];
    const float* qb2 = (const float*)d_in[22];

    float* ws = (float*)d_ws;
    float* qbuf = ws;                              // 0 .. 1,280,000
    float* Dg   = ws + 1280000;                    // N*16
    float* Pg   = ws + 1440000;                    // N*48 (contiguous with Dg)
    float* cdst = ws + 1920000;                    // N*256 f32 -> 4,480,000
    unsigned short* csrc_bf = (unsigned short*)(ws + 4480000);  // N*256 halves -> 5,760,000
    unsigned short* h_bf = (unsigned short*)(ws + 5760000);     // N*128 halves -> 6,400,000
    unsigned short* Wt1  = (unsigned short*)(ws + 6400000);     // -> 6,445,056
    unsigned short* kW2t = (unsigned short*)(ws + 6445056);     // -> 6,453,248
    unsigned short* vW2t = (unsigned short*)(ws + 6453248);     // -> 6,454,272
    unsigned short* qW1t = (unsigned short*)(ws + 6454272);     // -> 6,462,464
    unsigned short* qW2t = (unsigned short*)(ws + 6462464);     // -> 6,470,656
    int* cnt  = (int*)(ws + 6470656);              // -> 6,480,656
    int* cnt2 = (int*)(ws + 6480656);              // -> 6,490,656
    float* edata2 = ws + 6490656;                  // E*8 -> 9,050,656
    float* out = (float*)d_out;

    hipMemsetAsync(cnt, 0, NN * sizeof(int), stream);
    hipMemsetAsync(Dg, 0, NN * 64 * sizeof(float), stream);   // Dg + Pg contiguous
    hipLaunchKernelGGL(k_pre,   dim3(PRE_HIST + PRE_PREP), dim3(256), 0, stream,
                       ei, cnt, h, kW1, vW1, kW2, vW2, qW1, qW2,
                       h_bf, Wt1, kW2t, vW2t, qW1t, qW2t);
    hipLaunchKernelGGL(k_scan,  dim3(1),    dim3(1024), 0, stream, cnt, cnt2);
    hipLaunchKernelGGL(k_placeq, dim3(PQ_PLACE + PQ_QMLP + PQ_CPREP), dim3(256), 0, stream,
                       ei, cnt2, x, ea, edata2, h_bf, Wt1, kb1, vb1,
                       qW1t, qb1, qg, qbt, qW2t, qb2, qbuf, cdst, csrc_bf);
    hipLaunchKernelGGL(k_edge,  dim3(5000), dim3(512),  0, stream,
                       edata2, Wt1, cdst, csrc_bf,
                       kg, kbt, vg, vbt,
                       kW2t, kb2, vW2t, vb2,
                       qbuf, Dg, Pg);
    hipLaunchKernelGGL(k_fin,   dim3(40),   dim3(256),  0, stream, Dg, Pg, out);
}

// Round 15
// 213.511 us; speedup vs baseline: 1.0655x; 1.0311x over previous
//
#include <hip/hip_runtime.h>
#include <hip/hip_bf16.h>
#include <math.h>

typedef __attribute__((ext_vector_type(8))) short short8;
typedef __attribute__((ext_vector_type(4))) float f32x4;

#define NN 10000
#define EE 320000
#define NHEAD 16
#define EPSf 1e-5f

// ---------- bf16 helpers ----------
__device__ __forceinline__ unsigned short f2bf(float f) {
    union { float f; unsigned u; } v; v.f = f;
    unsigned u = v.u;
    u += 0x7fffu + ((u >> 16) & 1u);   // RNE
    return (unsigned short)(u >> 16);
}
__device__ __forceinline__ unsigned pk2(float a, float b) {
    __hip_bfloat162 t = __float22bfloat162_rn(make_float2(a, b));
    return *reinterpret_cast<unsigned*>(&t);
}
__device__ __forceinline__ float bfLo(unsigned u) { return __uint_as_float(u << 16); }
__device__ __forceinline__ float bfHi(unsigned u) { return __uint_as_float(u & 0xFFFF0000u); }

// sEX/sVl overlays on Y's k-half byte region (rows 0..15 / 16..31)
__device__ __forceinline__ float& sEXat(unsigned short* sR, int ix) {
    return *(float*)(sR + ((ix >> 6) << 8) + ((ix & 63) << 1));
}
__device__ __forceinline__ float& sVLat(unsigned short* sR, int ix) {
    return *(float*)(sR + 4096 + ((ix >> 6) << 8) + ((ix & 63) << 1));
}

// ed-tile slot: 12 chunks/row, XOR swizzle within aligned groups (8 + 4)
__device__ __forceinline__ int edslot(int r, int cl) {
    int c = (cl < 8) ? (cl ^ (r & 7)) : (8 + ((cl & 3) ^ (r & 3)));
    return r * 96 + (c << 3);
}

// ---------- fused: hist (1250) + prep (1802) ----------
// Wt1 ed-block k' order: [ea(4) | gauss(80) | zeros(12)] at k' 256..351
#define PRE_HIST 1250
#define PRE_PREP 1802
__global__ __launch_bounds__(256) void k_pre(
    const int* __restrict__ ei, int* __restrict__ cnt,
    const float* __restrict__ h,
    const float* __restrict__ kW1, const float* __restrict__ vW1,
    const float* __restrict__ kW2, const float* __restrict__ vW2,
    const float* __restrict__ qW1, const float* __restrict__ qW2,
    unsigned short* __restrict__ h_bf, unsigned short* __restrict__ Wt1,
    unsigned short* __restrict__ kW2t, unsigned short* __restrict__ vW2t,
    unsigned short* __restrict__ qW1t, unsigned short* __restrict__ qW2t)
{
    const int tid = threadIdx.x;
    int b = blockIdx.x;

    if (b < PRE_HIST) {                       // ---- histogram ----
        int e = b * 256 + tid;                // EE = 1250*256 exactly
        atomicAdd(&cnt[ei[EE + e]], 1);
        return;
    }
    b -= PRE_HIST;                            // ---- prep ----
    int i = b * 256 + tid;
    if (i < 320000) {                         // h: 4 elements per thread
        float4 v = *(const float4*)(h + i * 4);
        uint2 o; o.x = pk2(v.x, v.y); o.y = pk2(v.z, v.w);
        *(uint2*)(h_bf + i * 4) = o;
        return;
    }
    int j = i - 320000;
    if (j < 256 * 352) {
        int n = j / 352, k = j % 352;
        float val = 0.f;
        int pk = -1;
        if (k < 128)      pk = 84 + k;            // h_dst
        else if (k < 256) pk = 212 + (k - 128);   // h_src
        else if (k < 260) pk = k - 256;           // ea
        else if (k < 340) pk = 4 + (k - 260);     // gauss
        if (pk >= 0)
            val = (n < 128) ? kW1[pk * 128 + n] : vW1[pk * 128 + (n - 128)];
        Wt1[j] = f2bf(val); return;
    }
    j -= 256 * 352;
    if (j < 128 * 128) { int n = j >> 7, k = j & 127; kW2t[j] = f2bf(kW2[k * 128 + n]); return; }
    j -= 128 * 128;
    if (j < 16 * 128)  { int n = j >> 7, k = j & 127; vW2t[j] = f2bf(vW2[k * 16 + n]); return; }
    j -= 16 * 128;
    if (j < 128 * 128) { int n = j >> 7, k = j & 127; qW1t[j] = f2bf(qW1[k * 128 + n]); return; }
    j -= 128 * 128;
    if (j < 128 * 128) { int n = j >> 7, k = j & 127; qW2t[j] = f2bf(qW2[k * 128 + n]); return; }
}

// ---------------------- scan (wave-based) ----------------------
__global__ __launch_bounds__(1024) void k_scan(const int* __restrict__ cnt,
                                               int* __restrict__ cnt2) {
    __shared__ int wsum[16];
    const int t = threadIdx.x;
    const int lane = t & 63, w = t >> 6;
    int loc[10];
    int s = 0;
    #pragma unroll
    for (int i = 0; i < 10; ++i) {
        int idx = t * 10 + i;
        loc[i] = (idx < NN) ? cnt[idx] : 0;
        s += loc[i];
    }
    int sc = s;
    #pragma unroll
    for (int off = 1; off < 64; off <<= 1) {
        int v = __shfl_up(sc, off, 64);
        if (lane >= off) sc += v;
    }
    if (lane == 63) wsum[w] = sc;
    __syncthreads();
    if (w == 0) {
        int v = (lane < 16) ? wsum[lane] : 0;
        int c = v;
        #pragma unroll
        for (int off = 1; off < 16; off <<= 1) {
            int t2 = __shfl_up(c, off, 64);
            if (lane >= off) c += t2;
        }
        if (lane < 16) wsum[lane] = c - v;
    }
    __syncthreads();
    int run = wsum[w] + sc - s;
    #pragma unroll
    for (int i = 0; i < 10; ++i) {
        int idx = t * 10 + i;
        if (idx < NN) { cnt2[idx] = run; run += loc[i]; }
    }
}

// ---- fused: place+edata (1250) + q-MLP (157) + c-table precompute (157) ----
#define PQ_PLACE 1250
#define PQ_QMLP  157
#define PQ_CPREP 157
__global__ __launch_bounds__(256) void k_placeq(
    const int* __restrict__ ei, int* __restrict__ cnt2,
    const float* __restrict__ x, const float* __restrict__ ea,
    float* __restrict__ edata2,
    const unsigned short* __restrict__ h_bf,
    const unsigned short* __restrict__ Wt1,
    const float* __restrict__ kb1, const float* __restrict__ vb1,
    const unsigned short* __restrict__ qW1t, const float* __restrict__ qb1,
    const float* __restrict__ qg,  const float* __restrict__ qbt,
    const unsigned short* __restrict__ qW2t, const float* __restrict__ qb2,
    float* __restrict__ qout,
    float* __restrict__ cdst, unsigned short* __restrict__ csrc_bf)
{
    __shared__ __align__(16) unsigned short sQ[64 * 128];
    __shared__ float2 sSt[4 * 64];
    const int tid = threadIdx.x;
    int b = blockIdx.x;

    if (b < PQ_PLACE) {                       // ---- place + edata2 pack ----
        int e = b * 256 + tid;
        int s = ei[e], d = ei[EE + e];
        int slot = atomicAdd(&cnt2[d], 1);
        float rx = x[d*3+0] - x[s*3+0];
        float ry = x[d*3+1] - x[s*3+1];
        float rz = x[d*3+2] - x[s*3+2];
        float dist = sqrtf(rx*rx + ry*ry + rz*rz);
        float4 eav = *(const float4*)(ea + e * 4);
        float* ep = edata2 + (size_t)slot * 8;
        ep[0] = rx; ep[1] = ry; ep[2] = rz; ep[3] = dist;
        unsigned* epu = (unsigned*)ep;
        epu[4] = pk2(eav.x, eav.y);
        epu[5] = pk2(eav.z, eav.w);
        ((int*)ep)[6] = s; ((int*)ep)[7] = d;
        return;
    }
    b -= PQ_PLACE;
    const int lane = tid & 63, wv = tid >> 6, rA = lane & 15, kq = lane >> 4;
    f32x4 zf = {0.f, 0.f, 0.f, 0.f};

    if (b >= PQ_QMLP) {                       // ---- c-table precompute ----
        b -= PQ_QMLP;
        const int n0c = b * 64;
        #pragma unroll
        for (int it = 0; it < 4; ++it) {
            int p = tid + it * 256;
            int r = p >> 4, c = p & 15;
            int node = n0c + r; if (node >= NN) node = NN - 1;
            uint4 v = *(const uint4*)(h_bf + node * 128 + c * 8);
            *(uint4*)(sQ + r * 128 + ((c ^ (r & 7)) << 3)) = v;
        }
        __syncthreads();
        const int n0w = wv * 64;              // 4 waves x 64 cols
        #pragma unroll
        for (int T = 0; T < 2; ++T) {
            const int Toff = T << 7;
            f32x4 a[4][4];
            #pragma unroll
            for (int nf = 0; nf < 4; ++nf)
                #pragma unroll
                for (int ef = 0; ef < 4; ++ef) a[nf][ef] = zf;
            for (int k0 = 0; k0 < 128; k0 += 32) {
                int cb = (k0 >> 3) + kq;
                short8 wf[4], kv[4];
                #pragma unroll
                for (int nf = 0; nf < 4; ++nf)
                    wf[nf] = *(const short8*)(Wt1 + (n0w + nf * 16 + rA) * 352 + Toff + k0 + kq * 8);
                #pragma unroll
                for (int ef = 0; ef < 4; ++ef) {
                    int r = ef * 16 + rA;
                    kv[ef] = *(const short8*)(sQ + r * 128 + ((cb ^ (r & 7)) << 3));
                }
                #pragma unroll
                for (int nf = 0; nf < 4; ++nf)
                    #pragma unroll
                    for (int ef = 0; ef < 4; ++ef)
                        a[nf][ef] = __builtin_amdgcn_mfma_f32_16x16x32_bf16(wf[nf], kv[ef], a[nf][ef], 0, 0, 0);
            }
            if (T == 0) {
                #pragma unroll
                for (int nf = 0; nf < 4; ++nf) {
                    int col = n0w + nf * 16 + kq * 4;
                    f32x4 bb = (col < 128) ? *(const f32x4*)(kb1 + col)
                                           : *(const f32x4*)(vb1 + col - 128);
                    #pragma unroll
                    for (int ef = 0; ef < 4; ++ef) {
                        int node = n0c + ef * 16 + rA;
                        if (node < NN) {
                            f32x4 o;
                            #pragma unroll
                            for (int j = 0; j < 4; ++j) o[j] = a[nf][ef][j] + bb[j];
                            *(f32x4*)(cdst + (size_t)node * 256 + col) = o;
                        }
                    }
                }
            } else {
                #pragma unroll
                for (int nf = 0; nf < 4; ++nf) {
                    int col = n0w + nf * 16 + kq * 4;
                    #pragma unroll
                    for (int ef = 0; ef < 4; ++ef) {
                        int node = n0c + ef * 16 + rA;
                        if (node < NN) {
                            uint2 pw;
                            pw.x = pk2(a[nf][ef][0], a[nf][ef][1]);
                            pw.y = pk2(a[nf][ef][2], a[nf][ef][3]);
                            *(uint2*)(csrc_bf + (size_t)node * 256 + col) = pw;
                        }
                    }
                }
            }
        }
        return;
    }
    // ---- q-MLP (MFMA) ----
    const int n0q = b * 64;
    #pragma unroll
    for (int it = 0; it < 4; ++it) {
        int p = tid + it * 256;
        int r = p >> 4, c = p & 15;
        int node = n0q + r; if (node >= NN) node = NN - 1;
        uint4 v = *(const uint4*)(h_bf + node * 128 + c * 8);
        *(uint4*)(sQ + r * 128 + ((c ^ (r & 7)) << 3)) = v;
    }
    __syncthreads();

    const int nb = wv * 32;
    f32x4 acc[2][4];
    #pragma unroll
    for (int nf = 0; nf < 2; ++nf)
        #pragma unroll
        for (int ef = 0; ef < 4; ++ef) acc[nf][ef] = zf;

    for (int k0 = 0; k0 < 128; k0 += 32) {
        int cb = (k0 >> 3) + kq;
        short8 wf[2], kv[4];
        #pragma unroll
        for (int nf = 0; nf < 2; ++nf)
            wf[nf] = *(const short8*)(qW1t + (nb + nf * 16 + rA) * 128 + k0 + kq * 8);
        #pragma unroll
        for (int ef = 0; ef < 4; ++ef) {
            int r = ef * 16 + rA;
            kv[ef] = *(const short8*)(sQ + r * 128 + ((cb ^ (r & 7)) << 3));
        }
        #pragma unroll
        for (int nf = 0; nf < 2; ++nf)
            #pragma unroll
            for (int ef = 0; ef < 4; ++ef)
                acc[nf][ef] = __builtin_amdgcn_mfma_f32_16x16x32_bf16(wf[nf], kv[ef], acc[nf][ef], 0, 0, 0);
    }
    #pragma unroll
    for (int nf = 0; nf < 2; ++nf) {
        f32x4 bb = *(const f32x4*)(qb1 + nb + nf * 16 + kq * 4);
        #pragma unroll
        for (int ef = 0; ef < 4; ++ef)
            #pragma unroll
            for (int j = 0; j < 4; ++j) acc[nf][ef][j] += bb[j];
    }
    float sm[4], sq2[4];
    #pragma unroll
    for (int ef = 0; ef < 4; ++ef) {
        float s = 0.f, s2 = 0.f;
        #pragma unroll
        for (int nf = 0; nf < 2; ++nf)
            #pragma unroll
            for (int j = 0; j < 4; ++j) { float v = acc[nf][ef][j]; s += v; s2 += v * v; }
        s  += __shfl_xor(s, 16, 64);  s  += __shfl_xor(s, 32, 64);
        s2 += __shfl_xor(s2, 16, 64); s2 += __shfl_xor(s2, 32, 64);
        sm[ef] = s; sq2[ef] = s2;
    }
    if (kq == 0) {
        #pragma unroll
        for (int ef = 0; ef < 4; ++ef)
            sSt[wv * 64 + ef * 16 + rA] = make_float2(sm[ef], sq2[ef]);
    }
    __syncthreads();

    {
        f32x4 g4[2], b4[2];
        #pragma unroll
        for (int nf = 0; nf < 2; ++nf) {
            g4[nf] = *(const f32x4*)(qg  + nb + nf * 16 + kq * 4);
            b4[nf] = *(const f32x4*)(qbt + nb + nf * 16 + kq * 4);
        }
        #pragma unroll
        for (int ef = 0; ef < 4; ++ef) {
            int r = ef * 16 + rA;
            float ts = 0.f, ts2 = 0.f;
            #pragma unroll
            for (int w2 = 0; w2 < 4; ++w2) {
                float2 p = sSt[w2 * 64 + r];
                ts += p.x; ts2 += p.y;
            }
            float mu  = ts * (1.f / 128.f);
            float var = ts2 * (1.f / 128.f) - mu * mu;
            float rs  = rsqrtf(var + EPSf);
            #pragma unroll
            for (int nf = 0; nf < 2; ++nf) {
                float y[4];
                #pragma unroll
                for (int j = 0; j < 4; ++j) {
                    float f = (acc[nf][ef][j] - mu) * rs * g4[nf][j] + b4[nf][j];
                    y[j] = f > 0.f ? f : 0.f;
                }
                int col = nb + nf * 16 + kq * 4;
                int ch = col >> 3;
                uint2 pw; pw.x = pk2(y[0], y[1]); pw.y = pk2(y[2], y[3]);
                *(uint2*)(sQ + r * 128 + ((ch ^ (r & 7)) << 3) + (col & 7)) = pw;
            }
        }
    }
    __syncthreads();

    f32x4 a2[2][4];
    #pragma unroll
    for (int nf = 0; nf < 2; ++nf)
        #pragma unroll
        for (int ef = 0; ef < 4; ++ef) a2[nf][ef] = zf;
    for (int k0 = 0; k0 < 128; k0 += 32) {
        int cb = (k0 >> 3) + kq;
        short8 wf[2], yv[4];
        #pragma unroll
        for (int nf = 0; nf < 2; ++nf)
            wf[nf] = *(const short8*)(qW2t + (nb + nf * 16 + rA) * 128 + k0 + kq * 8);
        #pragma unroll
        for (int ef = 0; ef < 4; ++ef) {
            int r = ef * 16 + rA;
            yv[ef] = *(const short8*)(sQ + r * 128 + ((cb ^ (r & 7)) << 3));
        }
        #pragma unroll
        for (int nf = 0; nf < 2; ++nf)
            #pragma unroll
            for (int ef = 0; ef < 4; ++ef)
                a2[nf][ef] = __builtin_amdgcn_mfma_f32_16x16x32_bf16(wf[nf], yv[ef], a2[nf][ef], 0, 0, 0);
    }
    #pragma unroll
    for (int nf = 0; nf < 2; ++nf) {
        f32x4 bb = *(const f32x4*)(qb2 + nb + nf * 16 + kq * 4);
        #pragma unroll
        for (int ef = 0; ef < 4; ++ef) {
            int node = n0q + ef * 16 + rA;
            if (node < NN) {
                f32x4 o;
                #pragma unroll
                for (int j = 0; j < 4; ++j) o[j] = a2[nf][ef][j] + bb[j];
                *(f32x4*)(qout + node * 128 + nb + nf * 16 + kq * 4) = o;
            }
        }
    }
}

// ------- per-slot kernel (XCD-swizzled): LDS prologue, c-gather, K=96 MFMA, fused epilogue -------
__global__ __launch_bounds__(512) void k_edge(
    const float* __restrict__ edata2,
    const unsigned short* __restrict__ Wt1,
    const float* __restrict__ cdst, const unsigned short* __restrict__ csrc_bf,
    const float* __restrict__ kg, const float* __restrict__ kbt,
    const float* __restrict__ vg, const float* __restrict__ vbt,
    const unsigned short* __restrict__ kW2t, const float* __restrict__ kb2,
    const unsigned short* __restrict__ vW2t, const float* __restrict__ vb2,
    const float* __restrict__ q,
    float* __restrict__ Dg, float* __restrict__ Pg)
{
    // sY (32KB) time-multiplexed: ed tile [64][96] -> Y [64][256] -> EX/V overlay.
    __shared__ __align__(16) unsigned short sY[64 * 256];
    __shared__ float2 sStats[8 * 64];
    __shared__ float sEA[64 * 4];
    __shared__ float sRel[64 * 3];
    __shared__ float sDist[64];
    __shared__ int   sSrc[64], sDst[64];
    unsigned short* sED = sY;   // alias (layout per edslot)

    const int tid  = threadIdx.x;
    // XCD swizzle: grid 5000 = 8 * 625 (bijective)
    const int bid  = blockIdx.x;
    const int e0   = ((bid & 7) * 625 + (bid >> 3)) * 64;
    const int lane = tid & 63;
    const int wv   = tid >> 6;          // 0..7
    const int rA   = lane & 15;
    const int kq   = lane >> 4;

    if (tid < 64) {
        const float* ep = edata2 + (size_t)(e0 + tid) * 8;
        f32x4 w0 = *(const f32x4*)ep;            // rx, ry, rz, dist
        uint2 eap = *(const uint2*)((const unsigned*)ep + 4);
        int2  sd = *(const int2*)((const int*)ep + 6);
        sRel[tid*3+0] = w0[0]; sRel[tid*3+1] = w0[1]; sRel[tid*3+2] = w0[2];
        sDist[tid] = w0[3];
        sEA[tid*4+0] = bfLo(eap.x); sEA[tid*4+1] = bfHi(eap.x);
        sEA[tid*4+2] = bfLo(eap.y); sEA[tid*4+3] = bfHi(eap.y);
        sSrc[tid] = sd.x; sDst[tid] = sd.y;
    }
    __syncthreads();

    // ---- per-thread src/dst + pre-issued c-gather loads ----
    const int n0 = wv * 32;
    int dn[4], sn[4];
    #pragma unroll
    for (int ef = 0; ef < 4; ++ef) {
        int rr = ef * 16 + rA;
        dn[ef] = sDst[rr]; sn[ef] = sSrc[rr];
    }
    f32x4 cdv[2][4];
    uint2 csv[2][4];
    #pragma unroll
    for (int ef = 0; ef < 4; ++ef)
        #pragma unroll
        for (int nf = 0; nf < 2; ++nf) {
            cdv[nf][ef] = *(const f32x4*)(cdst + (size_t)dn[ef] * 256 + n0 + nf * 16 + kq * 4);
            csv[nf][ef] = *(const uint2*)(csrc_bf + (size_t)sn[ef] * 256 + n0 + nf * 16 + kq * 4);
        }

    // ---- stage ed features [64][96] (dist/ea from LDS) ----
    const float step  = 10.0f / 19.0f;
    const float coeff = -0.5f / (step * step);
    #pragma unroll
    for (int it = 0; it < 2; ++it) {
        int p = tid + it * 512;
        if (p < 768) {
            int r = (p * 5462) >> 16;        // p / 12
            int cl = p - r * 12;
            float dist = sDist[r];
            int i0 = cl * 8;
            float v[8];
            #pragma unroll
            for (int j = 0; j < 8; ++j) {
                int i = i0 + j;
                float val;
                if (i < 4) val = sEA[r*4 + i];
                else if (i < 84) {
                    int im4 = i - 4;
                    int f = (im4 * 3277) >> 16;   // im4 / 20
                    int gg = im4 - f * 20;
                    float dd = dist - (float)gg * step;
                    val = sEA[r*4 + f] * __expf(coeff * dd * dd);
                } else val = 0.f;
                v[j] = val;
            }
            uint4 pw;
            pw.x = pk2(v[0], v[1]); pw.y = pk2(v[2], v[3]);
            pw.z = pk2(v[4], v[5]); pw.w = pk2(v[6], v[7]);
            *(uint4*)(sED + edslot(r, cl)) = pw;
        }
    }
    __syncthreads();

    // ---- seed acc (gather loads drained under staging) ----
    f32x4 zf = {0.f, 0.f, 0.f, 0.f};
    f32x4 acc[2][4];
    #pragma unroll
    for (int ef = 0; ef < 4; ++ef)
        #pragma unroll
        for (int nf = 0; nf < 2; ++nf) {
            f32x4 cs;
            cs[0] = bfLo(csv[nf][ef].x);
            cs[1] = bfHi(csv[nf][ef].x);
            cs[2] = bfLo(csv[nf][ef].y);
            cs[3] = bfHi(csv[nf][ef].y);
            acc[nf][ef] = cdv[nf][ef] + cs;
        }

    // ---- ed MFMA: K = 96 (weights at Wt1 k' 256..351) ----
    #pragma unroll
    for (int s = 0; s < 3; ++s) {
        int k0 = s * 32;
        short8 wfr[2], kv[4];
        #pragma unroll
        for (int nf = 0; nf < 2; ++nf)
            wfr[nf] = *(const short8*)(Wt1 + (n0 + nf * 16 + rA) * 352 + 256 + k0 + kq * 8);
        #pragma unroll
        for (int ef = 0; ef < 4; ++ef) {
            int r = ef * 16 + rA;
            kv[ef] = *(const short8*)(sED + edslot(r, s * 4 + kq));
        }
        #pragma unroll
        for (int nf = 0; nf < 2; ++nf)
            #pragma unroll
            for (int ef = 0; ef < 4; ++ef)
                acc[nf][ef] = __builtin_amdgcn_mfma_f32_16x16x32_bf16(wfr[nf], kv[ef], acc[nf][ef], 0, 0, 0);
    }

    // ---- in-register LN stats ----
    float sm[4], sq2[4];
    #pragma unroll
    for (int ef = 0; ef < 4; ++ef) {
        float s = 0.f, s2 = 0.f;
        #pragma unroll
        for (int nf = 0; nf < 2; ++nf)
            #pragma unroll
            for (int j = 0; j < 4; ++j) { float v = acc[nf][ef][j]; s += v; s2 += v * v; }
        s  += __shfl_xor(s, 16, 64);  s  += __shfl_xor(s, 32, 64);
        s2 += __shfl_xor(s2, 16, 64); s2 += __shfl_xor(s2, 32, 64);
        sm[ef] = s; sq2[ef] = s2;
    }
    if (kq == 0) {
        #pragma unroll
        for (int ef = 0; ef < 4; ++ef)
            sStats[wv * 64 + ef * 16 + rA] = make_float2(sm[ef], sq2[ef]);
    }
    __syncthreads();   // stats ready; separates sED reads from sY writes

    // ---- normalize + ReLU + pack -> Y ----
    {
        const float* gp = (wv < 4) ? kg : vg;
        const float* bp = (wv < 4) ? kbt : vbt;
        const int sb = (wv < 4) ? 0 : 4;
        f32x4 g4[2], b4[2];
        #pragma unroll
        for (int nf = 0; nf < 2; ++nf) {
            int cl = (wv & 3) * 32 + nf * 16 + kq * 4;
            g4[nf] = *(const f32x4*)(gp + cl);
            b4[nf] = *(const f32x4*)(bp + cl);
        }
        #pragma unroll
        for (int ef = 0; ef < 4; ++ef) {
            int e = ef * 16 + rA;
            float ts = 0.f, ts2 = 0.f;
            #pragma unroll
            for (int i = 0; i < 4; ++i) {
                float2 p = sStats[(sb + i) * 64 + e];
                ts += p.x; ts2 += p.y;
            }
            float mu  = ts * (1.f / 128.f);
            float var = ts2 * (1.f / 128.f) - mu * mu;
            float rs  = rsqrtf(var + EPSf);
            #pragma unroll
            for (int nf = 0; nf < 2; ++nf) {
                float y[4];
                #pragma unroll
                for (int j = 0; j < 4; ++j) {
                    float rsg = rs * g4[nf][j];
                    float f = fmaf(acc[nf][ef][j], rsg, fmaf(-mu, rsg, b4[nf][j]));
                    y[j] = f > 0.f ? f : 0.f;
                }
                int col = n0 + nf * 16 + kq * 4;
                int ch = col >> 3;
                uint2 pw; pw.x = pk2(y[0], y[1]); pw.y = pk2(y[2], y[3]);
                *(uint2*)(sY + e * 256 + ((ch ^ (e & 7)) << 3) + (col & 7)) = pw;
            }
        }
    }
    __syncthreads();

    // ---- q prefetch ----
    const int n0k = wv * 16;
    f32x4 qv[4];
    #pragma unroll
    for (int ef = 0; ef < 4; ++ef)
        qv[ef] = *(const f32x4*)(q + (size_t)dn[ef] * 128 + n0k + kq * 4);

    // ---- layer 2 (k) + logits: wave owns 16 cols ----
    float ps[4];
    {
        f32x4 a2[4];
        #pragma unroll
        for (int ef = 0; ef < 4; ++ef) a2[ef] = zf;
        for (int k0 = 0; k0 < 128; k0 += 32) {
            int cbase = (k0 >> 3) + kq;
            short8 wf2 = *(const short8*)(kW2t + (n0k + rA) * 128 + k0 + kq * 8);
            short8 yf[4];
            #pragma unroll
            for (int ef = 0; ef < 4; ++ef) {
                int r = ef * 16 + rA;
                yf[ef] = *(const short8*)(sY + r * 256 + ((cbase ^ (r & 7)) << 3));
            }
            #pragma unroll
            for (int ef = 0; ef < 4; ++ef)
                a2[ef] = __builtin_amdgcn_mfma_f32_16x16x32_bf16(wf2, yf[ef], a2[ef], 0, 0, 0);
        }
        f32x4 bb2 = *(const f32x4*)(kb2 + n0k + kq * 4);
        #pragma unroll
        for (int ef = 0; ef < 4; ++ef) {
            float s = 0.f;
            #pragma unroll
            for (int j = 0; j < 4; ++j) s += qv[ef][j] * (a2[ef][j] + bb2[j]);
            ps[ef] = s;
        }
        #pragma unroll
        for (int ef = 0; ef < 4; ++ef)
            ps[ef] += __shfl_xor(ps[ef], 16, 64);
    }
    __syncthreads();   // Y k-half reads done -> overlay sEX/sVl

    // ---- write sEX; layer 2 (v) on waves 0..3 ----
    {
        int h_base = wv * 2 + (kq >> 1);
        #pragma unroll
        for (int ef = 0; ef < 4; ++ef) {
            bool act = ((kq & 1) == 0) ? (ef < 2) : (ef >= 2);
            if (act) {
                int e = ef * 16 + rA;
                sEXat(sY, h_base * 64 + e) = __expf(ps[ef] * 0.35355339059327373f);
            }
        }
    }
    if (wv < 4) {
        f32x4 av = zf;
        int r = wv * 16 + rA;
        for (int k0 = 0; k0 < 128; k0 += 32) {
            int cbase = 16 + (k0 >> 3) + kq;
            short8 yv  = *(const short8*)(sY + r * 256 + ((cbase ^ (r & 7)) << 3));
            short8 wfv = *(const short8*)(vW2t + rA * 128 + k0 + kq * 8);
            av = __builtin_amdgcn_mfma_f32_16x16x32_bf16(wfv, yv, av, 0, 0, 0);
        }
        f32x4 bv = *(const f32x4*)(vb2 + kq * 4);
        #pragma unroll
        for (int j = 0; j < 4; ++j)
            sVLat(sY, (kq * 4 + j) * 64 + r) = av[j] + bv[j];
    }
    __syncthreads();

    // ---- segmented scan: 4 windows x 16 slots ----
    {
        const int s    = lane & 15;
        const int win  = wv & 3;
        const int slot = win * 16 + s;
        const int node = sDst[slot];

        bool fl = (s == 0) || (sDst[slot] != sDst[slot - 1]);
        unsigned long long bal = __ballot(fl);
        unsigned fb = (unsigned)((bal >> ((lane >> 4) * 16)) & 0xFFFFull);

        unsigned pre = fb & ((2u << s) - 1);
        int sstart = 31 - __clz(pre);

        float rx = sRel[slot * 3 + 0], ry = sRel[slot * 3 + 1], rz = sRel[slot * 3 + 2];
        int hg = (wv >> 2) * 8 + (lane >> 4) * 2;
        float ex2[2], px[2], py[2], pz[2];
        #pragma unroll
        for (int j = 0; j < 2; ++j) {
            int hh = hg + j;
            float exv = sEXat(sY, hh * 64 + slot);
            float vv  = sVLat(sY, hh * 64 + slot);
            float m = exv * vv;
            ex2[j] = exv; px[j] = m * rx; py[j] = m * ry; pz[j] = m * rz;
        }
        #pragma unroll
        for (int st = 1; st <= 8; st <<= 1) {
            bool take = (s - st >= sstart);
            #pragma unroll
            for (int j = 0; j < 2; ++j) {
                float t0 = __shfl_up(ex2[j], st, 16);
                float t1 = __shfl_up(px[j],  st, 16);
                float t2 = __shfl_up(py[j],  st, 16);
                float t3 = __shfl_up(pz[j],  st, 16);
                if (take) { ex2[j] += t0; px[j] += t1; py[j] += t2; pz[j] += t3; }
            }
        }
        bool isend = (s == 15) || ((fb >> (s + 1)) & 1u);
        if (isend) {
            #pragma unroll
            for (int j = 0; j < 2; ++j) {
                int hh = hg + j;
                atomicAdd(&Dg[node * 16 + hh], ex2[j]);
                atomicAdd(&Pg[node * 48 + 0 * 16 + hh], px[j]);
                atomicAdd(&Pg[node * 48 + 1 * 16 + hh], py[j]);
                atomicAdd(&Pg[node * 48 + 2 * 16 + hh], pz[j]);
            }
        }
    }
}

// ---------------------- finalize ----------------------
__global__ void k_fin(const float* __restrict__ Dg, const float* __restrict__ Pg,
                      float* __restrict__ out) {
    int n = blockIdx.x * 256 + threadIdx.x;
    if (n >= NN) return;
    float inv[16];
    #pragma unroll
    for (int hq = 0; hq < 4; ++hq) {
        f32x4 d = *(const f32x4*)(Dg + n * 16 + hq * 4);
        #pragma unroll
        for (int j = 0; j < 4; ++j) inv[hq * 4 + j] = (d[j] > 0.f) ? (1.f / d[j]) : 0.f;
    }
    #pragma unroll
    for (int c = 0; c < 3; ++c) {
        float s = 0.f;
        #pragma unroll
        for (int hq = 0; hq < 4; ++hq) {
            f32x4 p = *(const f32x4*)(Pg + n * 48 + c * 16 + hq * 4);
            #pragma unroll
            for (int j = 0; j < 4; ++j) s += p[j] * inv[hq * 4 + j];
        }
        out[n * 3 + c] = s * (1.f / 16.f);
    }
}

extern "C" void kernel_launch(void* const* d_in, const int* in_sizes, int n_in,
                              void* d_out, int out_size, void* d_ws, size_t ws_size,
                              hipStream_t stream) {
    const float* x   = (const float*)d_in[0];
    const float* h   = (const float*)d_in[1];
    const float* ea  = (const float*)d_in[2];
    const int*   ei  = (const int*)d_in[4];
    const float* kW1 = (const float*)d_in[5];
    const float* kb1 = (const float*)d_in[6];
    const float* kg  = (const float*)d_in[7];
    const float* kbt = (const float*)d_in[8];
    const float* kW2 = (const float*)d_in[9];
    const float* kb2 = (const float*)d_in[10];
    const float* vW1 = (const float*)d_in[11];
    const float* vb1 = (const float*)d_in[12];
    const float* vg  = (const float*)d_in[13];
    const float* vbt = (const float*)d_in[14];
    const float* vW2 = (const float*)d_in[15];
    const float* vb2 = (const float*)d_in[16];
    const float* qW1 = (const float*)d_in[17];
    const float* qb1 = (const float*)d_in[18];
    const float* qg  = (const float*)d_in[19];
    const float* qbt = (const float*)d_in[20];
    const float* qW2 = (const float*)d_in[21];
    const float* qb2 = (const float*)d_in[22];

    float* ws = (float*)d_ws;
    float* qbuf = ws;                              // 0 .. 1,280,000
    float* Dg   = ws + 1280000;                    // N*16
    float* Pg   = ws + 1440000;                    // N*48 (contiguous with Dg)
    float* cdst = ws + 1920000;                    // N*256 f32 -> 4,480,000
    unsigned short* csrc_bf = (unsigned short*)(ws + 4480000);  // N*256 halves -> 5,760,000
    unsigned short* h_bf = (unsigned short*)(ws + 5760000);     // N*128 halves -> 6,400,000
    unsigned short* Wt1  = (unsigned short*)(ws + 6400000);     // -> 6,445,056
    unsigned short* kW2t = (unsigned short*)(ws + 6445056);     // -> 6,453,248
    unsigned short* vW2t = (unsigned short*)(ws + 6453248);     // -> 6,454,272
    unsigned short* qW1t = (unsigned short*)(ws + 6454272);     // -> 6,462,464
    unsigned short* qW2t = (unsigned short*)(ws + 6462464);     // -> 6,470,656
    int* cnt  = (int*)(ws + 6470656);              // -> 6,480,656
    int* cnt2 = (int*)(ws + 6480656);              // -> 6,490,656
    float* edata2 = ws + 6490656;                  // E*8 -> 9,050,656
    float* out = (float*)d_out;

    hipMemsetAsync(cnt, 0, NN * sizeof(int), stream);
    hipMemsetAsync(Dg, 0, NN * 64 * sizeof(float), stream);   // Dg + Pg contiguous
    hipLaunchKernelGGL(k_pre,   dim3(PRE_HIST + PRE_PREP), dim3(256), 0, stream,
                       ei, cnt, h, kW1, vW1, kW2, vW2, qW1, qW2,
                       h_bf, Wt1, kW2t, vW2t, qW1t, qW2t);
    hipLaunchKernelGGL(k_scan,  dim3(1),    dim3(1024), 0, stream, cnt, cnt2);
    hipLaunchKernelGGL(k_placeq, dim3(PQ_PLACE + PQ_QMLP + PQ_CPREP), dim3(256), 0, stream,
                       ei, cnt2, x, ea, edata2, h_bf, Wt1, kb1, vb1,
                       qW1t, qb1, qg, qbt, qW2t, qb2, qbuf, cdst, csrc_bf);
    hipLaunchKernelGGL(k_edge,  dim3(5000), dim3(512),  0, stream,
                       edata2, Wt1, cdst, csrc_bf,
                       kg, kbt, vg, vbt,
                       kW2t, kb2, vW2t, vb2,
                       qbuf, Dg, Pg);
    hipLaunchKernelGGL(k_fin,   dim3(40),   dim3(256),  0, stream, Dg, Pg, out);
}